// Round 8
// baseline (329.693 us; speedup 1.0000x reference)
//
#include <hip/hip_runtime.h>

#define N_EMBD 768
#define SEQ    1024
#define NBATCH 4
#define NHEAD  12
#define HDIM   64
#define NROWS  4096   // B*L
#define FFN    3072
#define W768   589824    // 768*768
#define WFC    2359296   // 3072*768
#define NCVT   6912      // (4*W768 + 2*WFC) / 1024

typedef unsigned short u16;
typedef __bf16 bf16x8 __attribute__((ext_vector_type(8)));
typedef float  f32x4  __attribute__((ext_vector_type(4)));
typedef unsigned short u16x8 __attribute__((ext_vector_type(8)));

typedef const __attribute__((address_space(1))) unsigned int gu32;
typedef __attribute__((address_space(3))) unsigned int lu32;
#define GLL(g, l) __builtin_amdgcn_global_load_lds((gu32*)(g), (lu32*)(l), 16, 0, 0)

__device__ __forceinline__ u16 f2bf(float f) {
    union { float f; unsigned int i; } v; v.f = f;
    unsigned int r = v.i + 0x7fffu + ((v.i >> 16) & 1u);
    return (u16)(r >> 16);
}

// ---------------- prep: cvt_weights + ln1 + prefix ----------------
__global__ __launch_bounds__(256) void prep_kernel(const float* __restrict__ qw,
                                                   const float* __restrict__ kw,
                                                   const float* __restrict__ vw,
                                                   const float* __restrict__ cw,
                                                   const float* __restrict__ fcw,
                                                   const float* __restrict__ pw,
                                                   u16* __restrict__ wdst,
                                                   const float* __restrict__ x,
                                                   const float* __restrict__ ln1w,
                                                   const float* __restrict__ ln1b,
                                                   u16* __restrict__ xn,
                                                   const int* __restrict__ mod_idx,
                                                   int* __restrict__ g) {
    int bx = blockIdx.x;
    if (bx < NCVT) {
        size_t e = ((size_t)bx * 256 + threadIdx.x) * 4;
        const float* src; size_t base;
        if      (e < 1 * (size_t)W768) { src = qw;  base = 0; }
        else if (e < 2 * (size_t)W768) { src = kw;  base = 1 * (size_t)W768; }
        else if (e < 3 * (size_t)W768) { src = vw;  base = 2 * (size_t)W768; }
        else if (e < 4 * (size_t)W768) { src = cw;  base = 3 * (size_t)W768; }
        else if (e < 4 * (size_t)W768 + WFC) { src = fcw; base = 4 * (size_t)W768; }
        else { src = pw; base = 4 * (size_t)W768 + WFC; }
        float4 v = *(const float4*)(src + (e - base));
        ushort4 o;
        o.x = f2bf(v.x); o.y = f2bf(v.y); o.z = f2bf(v.z); o.w = f2bf(v.w);
        *(ushort4*)(wdst + e) = o;
    } else if (bx < NCVT + 1024) {
        int row  = (bx - NCVT) * 4 + (threadIdx.x >> 6);
        int lane = threadIdx.x & 63;
        const float* p = x + (size_t)row * N_EMBD;
        float vals[12];
        float s = 0.f, sq = 0.f;
#pragma unroll
        for (int c = 0; c < 12; c++) {
            float v = p[c * 64 + lane];
            vals[c] = v; s += v; sq += v * v;
        }
#pragma unroll
        for (int o = 32; o > 0; o >>= 1) { s += __shfl_xor(s, o); sq += __shfl_xor(sq, o); }
        float mean = s * (1.0f / 768.0f);
        float var  = sq * (1.0f / 768.0f) - mean * mean;
        float r    = rsqrtf(var + 1e-5f);
        u16* d = xn + (size_t)row * N_EMBD;
#pragma unroll
        for (int c = 0; c < 12; c++) {
            int idx = c * 64 + lane;
            d[idx] = f2bf((vals[c] - mean) * r * ln1w[idx] + ln1b[idx]);
        }
    } else {
        __shared__ int sc[256];
        int b = bx - NCVT - 1024;
        int j = threadIdx.x;
        int4 mi = *(const int4*)(mod_idx + b * SEQ + j * 4);
        int f0 = (mi.x == 2), f1 = (mi.y == 2), f2v = (mi.z == 2), f3 = (mi.w == 2);
        int t1 = f0 + f1, t2 = t1 + f2v, t3 = t2 + f3;
        sc[j] = t3;
        __syncthreads();
        for (int off = 1; off < 256; off <<= 1) {
            int add = (j >= off) ? sc[j - off] : 0;
            __syncthreads();
            sc[j] += add;
            __syncthreads();
        }
        int excl = sc[j] - t3;
        int cin[4] = {excl + f0, excl + t1, excl + t2, excl + t3};
        int fl[4] = {f0, f1, f2v, f3};
#pragma unroll
        for (int i2 = 0; i2 < 4; i2++) {
            int jj = j * 4 + i2;
            int occ = fl[i2] ? (cin[i2] - 1) : (jj - cin[i2]);
            occ = occ < 0 ? 0 : (occ > 511 ? 511 : occ);
            g[b * SEQ + jj] = fl[i2] ? (b * 512 + occ) : (2048 + b * 512 + occ);
        }
    }
}

// ---------------- LayerNorm (fp32 in, bf16 out), one wave per row ----------------
__global__ __launch_bounds__(256) void ln_rows(const float* __restrict__ src,
                                               const float* __restrict__ src2,
                                               const int* __restrict__ g,
                                               const float* __restrict__ w,
                                               const float* __restrict__ b,
                                               u16* __restrict__ dst) {
    int row  = blockIdx.x * 4 + (threadIdx.x >> 6);
    int lane = threadIdx.x & 63;
    const float* p;
    if (g) {
        int gi = g[row];
        p = (gi < 2048) ? (src + (size_t)gi * N_EMBD)
                        : (src2 + (size_t)(gi - 2048) * N_EMBD);
    } else {
        p = src + (size_t)row * N_EMBD;
    }
    float vals[12];
    float s = 0.f, sq = 0.f;
#pragma unroll
    for (int c = 0; c < 12; c++) {
        float v = p[c * 64 + lane];
        vals[c] = v; s += v; sq += v * v;
    }
#pragma unroll
    for (int o = 32; o > 0; o >>= 1) { s += __shfl_xor(s, o); sq += __shfl_xor(sq, o); }
    float mean = s * (1.0f / 768.0f);
    float var  = sq * (1.0f / 768.0f) - mean * mean;
    float r    = rsqrtf(var + 1e-5f);
    u16* d = dst + (size_t)row * N_EMBD;
#pragma unroll
    for (int c = 0; c < 12; c++) {
        int idx = c * 64 + lane;
        d[idx] = f2bf((vals[c] - mean) * r * w[idx] + b[idx]);
    }
}

// ---------------- fused: x1 = pa+pb+cb+x ; hn = LN(x1) ----------------
__global__ __launch_bounds__(256) void ln2_fused(const float* __restrict__ pa,
                                                 const float* __restrict__ pb,
                                                 const float* __restrict__ cb,
                                                 const float* __restrict__ x,
                                                 const float* __restrict__ ln2w,
                                                 const float* __restrict__ ln2b,
                                                 float* __restrict__ x1,
                                                 u16* __restrict__ hn) {
    int row  = blockIdx.x * 4 + (threadIdx.x >> 6);
    int lane = threadIdx.x & 63;
    size_t base = (size_t)row * N_EMBD;
    float vals[12];
    float s = 0.f, sq = 0.f;
#pragma unroll
    for (int c = 0; c < 12; c++) {
        int idx = c * 64 + lane;
        float v = pa[base + idx] + pb[base + idx] + cb[idx] + x[base + idx];
        vals[c] = v; s += v; sq += v * v;
        x1[base + idx] = v;
    }
#pragma unroll
    for (int o = 32; o > 0; o >>= 1) { s += __shfl_xor(s, o); sq += __shfl_xor(sq, o); }
    float mean = s * (1.0f / 768.0f);
    float var  = sq * (1.0f / 768.0f) - mean * mean;
    float r    = rsqrtf(var + 1e-5f);
    u16* d = hn + base;
#pragma unroll
    for (int c = 0; c < 12; c++) {
        int idx = c * 64 + lane;
        d[idx] = f2bf((vals[c] - mean) * r * ln2w[idx] + ln2b[idx]);
    }
}

// ---------------- GEMM core: 64x128 tile, BK=32, GLL staging ----------------
__device__ __forceinline__ void core64(const u16* __restrict__ A, const u16* __restrict__ W,
                                       int K, int kBeg, int kEnd, int m0, int n0, int t,
                                       u16* As, u16* Bs, f32x4 (&acc)[2][4]) {
    int w = t >> 6, lane = t & 63, quad = lane >> 4, l16 = lane & 15;
    int r16 = lane >> 2, c8 = (lane & 3) * 8;
    int wm = (w >> 1) * 32, wn = (w & 1) * 64;
    for (int k0 = kBeg; k0 < kEnd; k0 += 32) {
        __syncthreads();
        const u16* gb = W + (size_t)(n0 + w * 32 + r16) * K + k0 + c8;
        GLL(A + (size_t)(m0 + w * 16 + r16) * K + k0 + c8, &As[(w * 16) * 32]);
        GLL(gb,                  &Bs[(w * 32) * 32]);
        GLL(gb + 16 * (size_t)K, &Bs[(w * 32 + 16) * 32]);
        __syncthreads();
        bf16x8 af[2], bfr[4];
#pragma unroll
        for (int i = 0; i < 2; i++)
            af[i] = *(const bf16x8*)&As[(wm + i * 16 + l16) * 32 + quad * 8];
#pragma unroll
        for (int j = 0; j < 4; j++)
            bfr[j] = *(const bf16x8*)&Bs[(wn + j * 16 + l16) * 32 + quad * 8];
#pragma unroll
        for (int i = 0; i < 2; i++)
#pragma unroll
            for (int j = 0; j < 4; j++)
                acc[i][j] = __builtin_amdgcn_mfma_f32_16x16x32_bf16(af[i], bfr[j], acc[i][j], 0, 0, 0);
    }
}

// ---------------- QKV: 64x128 tiles, z in {0,1,2} ----------------
__global__ __launch_bounds__(256) void gemm_qkv(const u16* __restrict__ xn,
                                                const u16* __restrict__ sn,
                                                const u16* __restrict__ wq,
                                                const float* __restrict__ qb,
                                                const float* __restrict__ kb,
                                                const float* __restrict__ vb,
                                                u16* __restrict__ outbase) {
    __shared__ u16 As[64 * 32], Bs[128 * 32];
    int z = blockIdx.z;
    const u16* A = (z == 0) ? xn : sn;
    const u16* W = wq + (size_t)z * W768;
    const float* bias = (z == 0) ? qb : ((z == 1) ? kb : vb);
    u16* C = outbase + (size_t)z * ((size_t)NROWS * N_EMBD);
    int m0 = blockIdx.y * 64, n0 = blockIdx.x * 128;
    int t = threadIdx.x;
    f32x4 acc[2][4];
#pragma unroll
    for (int i = 0; i < 2; i++)
#pragma unroll
        for (int j = 0; j < 4; j++) acc[i][j] = (f32x4){0.f, 0.f, 0.f, 0.f};
    core64(A, W, N_EMBD, 0, N_EMBD, m0, n0, t, As, Bs, acc);
    int w = t >> 6, lane = t & 63, quad = lane >> 4, l16 = lane & 15;
    int wm = (w >> 1) * 32, wn = (w & 1) * 64;
#pragma unroll
    for (int j = 0; j < 4; j++) {
        int col = n0 + wn + j * 16 + l16;
        float bv = bias[col];
#pragma unroll
        for (int i = 0; i < 2; i++) {
            int rowb = m0 + wm + i * 16 + quad * 4;
#pragma unroll
            for (int r = 0; r < 4; r++)
                C[(size_t)(rowb + r) * N_EMBD + col] = f2bf(acc[i][j][r] + bv);
        }
    }
}

// ---------------- fc: 64x128 tiles, K=768, fast GELU, bf16 out ----------------
__global__ __launch_bounds__(256) void gemm_fc(const u16* __restrict__ A,
                                               const u16* __restrict__ W,
                                               const float* __restrict__ bias,
                                               u16* __restrict__ C) {
    __shared__ u16 As[64 * 32], Bs[128 * 32];
    int m0 = blockIdx.y * 64, n0 = blockIdx.x * 128;
    int t = threadIdx.x;
    f32x4 acc[2][4];
#pragma unroll
    for (int i = 0; i < 2; i++)
#pragma unroll
        for (int j = 0; j < 4; j++) acc[i][j] = (f32x4){0.f, 0.f, 0.f, 0.f};
    core64(A, W, N_EMBD, 0, N_EMBD, m0, n0, t, As, Bs, acc);
    int w = t >> 6, lane = t & 63, quad = lane >> 4, l16 = lane & 15;
    int wm = (w >> 1) * 32, wn = (w & 1) * 64;
#pragma unroll
    for (int j = 0; j < 4; j++) {
        int col = n0 + wn + j * 16 + l16;
        float bv = bias[col];
#pragma unroll
        for (int i = 0; i < 2; i++) {
            int rowb = m0 + wm + i * 16 + quad * 4;
#pragma unroll
            for (int r = 0; r < 4; r++) {
                float v = acc[i][j][r] + bv;
                float y = v * (1.595769122f + 0.071354816f * v * v);
                float gel = v / (1.0f + __expf(-y));
                C[(size_t)(rowb + r) * FFN + col] = f2bf(gel);
            }
        }
    }
}

// ---------------- c-proj: 64x128, K=768 split-K x2, raw fp32 partials ----------
__global__ __launch_bounds__(256) void gemm_cproj_split(const u16* __restrict__ A,
                                                        const u16* __restrict__ W,
                                                        float* __restrict__ pa,
                                                        float* __restrict__ pb) {
    __shared__ u16 As[64 * 32], Bs[128 * 32];
    int z = blockIdx.z;
    float* P = z ? pb : pa;
    int m0 = blockIdx.y * 64, n0 = blockIdx.x * 128;
    int t = threadIdx.x;
    f32x4 acc[2][4];
#pragma unroll
    for (int i = 0; i < 2; i++)
#pragma unroll
        for (int j = 0; j < 4; j++) acc[i][j] = (f32x4){0.f, 0.f, 0.f, 0.f};
    core64(A, W, N_EMBD, z * 384, (z + 1) * 384, m0, n0, t, As, Bs, acc);
    int w = t >> 6, lane = t & 63, quad = lane >> 4, l16 = lane & 15;
    int wm = (w >> 1) * 32, wn = (w & 1) * 64;
#pragma unroll
    for (int j = 0; j < 4; j++) {
        int col = n0 + wn + j * 16 + l16;
#pragma unroll
        for (int i = 0; i < 2; i++) {
            int rowb = m0 + wm + i * 16 + quad * 4;
#pragma unroll
            for (int r = 0; r < 4; r++)
                P[(size_t)(rowb + r) * N_EMBD + col] = acc[i][j][r];
        }
    }
}

// ---------------- proj: 64x128, K=3072 split-K x3, fp32 partials ----------
__global__ __launch_bounds__(256) void gemm_proj_split(const u16* __restrict__ A,
                                                       const u16* __restrict__ W,
                                                       float* __restrict__ p0,
                                                       float* __restrict__ p1,
                                                       float* __restrict__ p2) {
    __shared__ u16 As[64 * 32], Bs[128 * 32];
    int z = blockIdx.z;
    float* P = (z == 0) ? p0 : ((z == 1) ? p1 : p2);
    int m0 = blockIdx.y * 64, n0 = blockIdx.x * 128;
    int t = threadIdx.x;
    f32x4 acc[2][4];
#pragma unroll
    for (int i = 0; i < 2; i++)
#pragma unroll
        for (int j = 0; j < 4; j++) acc[i][j] = (f32x4){0.f, 0.f, 0.f, 0.f};
    core64(A, W, FFN, z * 1024, (z + 1) * 1024, m0, n0, t, As, Bs, acc);
    int w = t >> 6, lane = t & 63, quad = lane >> 4, l16 = lane & 15;
    int wm = (w >> 1) * 32, wn = (w & 1) * 64;
#pragma unroll
    for (int j = 0; j < 4; j++) {
        int col = n0 + wn + j * 16 + l16;
#pragma unroll
        for (int i = 0; i < 2; i++) {
            int rowb = m0 + wm + i * 16 + quad * 4;
#pragma unroll
            for (int r = 0; r < 4; r++)
                P[(size_t)(rowb + r) * N_EMBD + col] = acc[i][j][r];
        }
    }
}

// out = p0 + p1 + out(=p2) + bias[col] + x1
__global__ __launch_bounds__(256) void reduce_proj(const float* __restrict__ p0,
                                                   const float* __restrict__ p1,
                                                   const float* __restrict__ bias,
                                                   const float* __restrict__ x1,
                                                   float* __restrict__ out) {
    size_t idx = ((size_t)blockIdx.x * 256 + threadIdx.x) * 4;
    int col = (int)(idx % N_EMBD);
    float4 a = *(const float4*)(p0 + idx);
    float4 b = *(const float4*)(p1 + idx);
    float4 c = *(const float4*)(out + idx);
    float4 r = *(const float4*)(x1 + idx);
    float4 bb = *(const float4*)(bias + col);
    float4 o;
    o.x = a.x + b.x + c.x + r.x + bb.x;
    o.y = a.y + b.y + c.y + r.y + bb.y;
    o.z = a.z + b.z + c.z + r.z + bb.z;
    o.w = a.w + b.w + c.w + r.w + bb.w;
    *(float4*)(out + idx) = o;
}

// ---------------- flash cross-attention (round-5 verified) ----------------
#define KST 72

__global__ __launch_bounds__(256) void attn_kernel(const u16* __restrict__ Q,
                                                   const u16* __restrict__ K,
                                                   const u16* __restrict__ V,
                                                   const float* __restrict__ age,
                                                   const float* __restrict__ mod_age,
                                                   u16* __restrict__ Y) {
    __shared__ u16 Kl[64 * KST];
    __shared__ u16 Vt[64 * KST];
    __shared__ u16 Pl[4][16 * KST];

    int bx = blockIdx.x;
    int qt = 15 - (bx / 48);
    int bh = bx % 48;
    int b = bh / NHEAD, h = bh % NHEAD;
    int t = threadIdx.x;
    int w = t >> 6, lane = t & 63, quad = lane >> 4, l16 = lane & 15;
    int q0 = qt * 64 + w * 16;

    size_t qrowbase = ((size_t)(b * SEQ + q0 + l16)) * N_EMBD + h * HDIM;
    bf16x8 qf0 = *(const bf16x8*)&Q[qrowbase + quad * 8];
    bf16x8 qf1 = *(const bf16x8*)&Q[qrowbase + 32 + quad * 8];

    float age_r[4];
#pragma unroll
    for (int r = 0; r < 4; r++) age_r[r] = age[b * SEQ + q0 + quad * 4 + r];
    float age_q0      = __shfl(age_r[0], 0);
    float age_max_blk = age[b * SEQ + qt * 64 + 63];
    float mod_min     = mod_age[b * SEQ];

    float mv0 = (lane < 16) ? mod_age[b * SEQ + lane * 64] : 1e30f;
    unsigned long long bm = __ballot(mv0 > age_max_blk);
    int nkt = bm ? (__ffsll(bm) - 1) : 16;

    int krow0 = t >> 3,        kc8 = (t & 7) * 8;
    int krow1 = 32 + (t >> 3);
    int vrow  = t & 63;
    int vc8_0 = t >> 6, vc8_1 = 4 + (t >> 6);

    float m_i[4] = {-1e30f, -1e30f, -1e30f, -1e30f};
    float l_i[4] = {0.f, 0.f, 0.f, 0.f};
    f32x4 o[4];
#pragma unroll
    for (int nt = 0; nt < 4; nt++) o[nt] = (f32x4){0.f, 0.f, 0.f, 0.f};

    u16x8 kr0, kr1, vr0, vr1;
    float mreg = 0.f;
    if (nkt > 0) {
        size_t kb = ((size_t)(b * SEQ)) * N_EMBD + h * HDIM;
        kr0 = *(const u16x8*)(K + kb + (size_t)krow0 * N_EMBD + kc8);
        kr1 = *(const u16x8*)(K + kb + (size_t)krow1 * N_EMBD + kc8);
        vr0 = *(const u16x8*)(V + kb + (size_t)vrow * N_EMBD + vc8_0 * 8);
        vr1 = *(const u16x8*)(V + kb + (size_t)vrow * N_EMBD + vc8_1 * 8);
        mreg = mod_age[b * SEQ + lane];
    }

    for (int kt = 0; kt < nkt; kt++) {
        __syncthreads();
        *(u16x8*)&Kl[krow0 * KST + kc8] = kr0;
        *(u16x8*)&Kl[krow1 * KST + kc8] = kr1;
#pragma unroll
        for (int e = 0; e < 8; e++) Vt[(vc8_0 * 8 + e) * KST + vrow] = vr0[e];
#pragma unroll
        for (int e = 0; e < 8; e++) Vt[(vc8_1 * 8 + e) * KST + vrow] = vr1[e];
        float mcur = mreg;
        __syncthreads();

        if (kt + 1 < nkt) {
            size_t kb = ((size_t)(b * SEQ + (kt + 1) * 64)) * N_EMBD + h * HDIM;
            kr0 = *(const u16x8*)(K + kb + (size_t)krow0 * N_EMBD + kc8);
            kr1 = *(const u16x8*)(K + kb + (size_t)krow1 * N_EMBD + kc8);
            vr0 = *(const u16x8*)(V + kb + (size_t)vrow * N_EMBD + vc8_0 * 8);
            vr1 = *(const u16x8*)(V + kb + (size_t)vrow * N_EMBD + vc8_1 * 8);
            mreg = mod_age[b * SEQ + (kt + 1) * 64 + lane];
        }

        float tile_max = __shfl(mcur, 63);
        bool need_mask = tile_max > age_q0;
        float p[4][4];
#pragma unroll
        for (int jt = 0; jt < 4; jt++) {
            f32x4 s = (f32x4){0.f, 0.f, 0.f, 0.f};
            bf16x8 kf0 = *(const bf16x8*)&Kl[(jt * 16 + l16) * KST + quad * 8];
            bf16x8 kf1 = *(const bf16x8*)&Kl[(jt * 16 + l16) * KST + 32 + quad * 8];
            s = __builtin_amdgcn_mfma_f32_16x16x32_bf16(qf0, kf0, s, 0, 0, 0);
            s = __builtin_amdgcn_mfma_f32_16x16x32_bf16(qf1, kf1, s, 0, 0, 0);
            float mval = __shfl(mcur, jt * 16 + l16);
#pragma unroll
            for (int r = 0; r < 4; r++) {
                float sv = s[r] * 0.125f;
                p[jt][r] = (!need_mask || mval <= age_r[r]) ? sv : -1e30f;
            }
        }
        float alpha[4];
#pragma unroll
        for (int r = 0; r < 4; r++) {
            float mx = fmaxf(fmaxf(p[0][r], p[1][r]), fmaxf(p[2][r], p[3][r]));
#pragma unroll
            for (int msk = 1; msk < 16; msk <<= 1) mx = fmaxf(mx, __shfl_xor(mx, msk));
            float mnew = fmaxf(m_i[r], mx);
            alpha[r] = __expf(m_i[r] - mnew);
            float srow = 0.f;
#pragma unroll
            for (int jt = 0; jt < 4; jt++) {
                float pv = __expf(p[jt][r] - mnew);
                p[jt][r] = pv;
                srow += pv;
            }
#pragma unroll
            for (int msk = 1; msk < 16; msk <<= 1) srow += __shfl_xor(srow, msk);
            l_i[r] = l_i[r] * alpha[r] + srow;
            m_i[r] = mnew;
        }
#pragma unroll
        for (int jt = 0; jt < 4; jt++)
#pragma unroll
            for (int r = 0; r < 4; r++)
                Pl[w][(quad * 4 + r) * KST + jt * 16 + l16] = f2bf(p[jt][r]);
#pragma unroll
        for (int nt = 0; nt < 4; nt++)
#pragma unroll
            for (int r = 0; r < 4; r++) o[nt][r] *= alpha[r];
#pragma unroll
        for (int c = 0; c < 2; c++) {
            bf16x8 pf = *(const bf16x8*)&Pl[w][l16 * KST + c * 32 + quad * 8];
#pragma unroll
            for (int nt = 0; nt < 4; nt++) {
                bf16x8 vf = *(const bf16x8*)&Vt[(nt * 16 + l16) * KST + c * 32 + quad * 8];
                o[nt] = __builtin_amdgcn_mfma_f32_16x16x32_bf16(pf, vf, o[nt], 0, 0, 0);
            }
        }
    }
#pragma unroll
    for (int r = 0; r < 4; r++) {
        int qrow = q0 + quad * 4 + r;
        float inv = (age_r[r] >= mod_min) ? (1.0f / l_i[r]) : 0.0f;
#pragma unroll
        for (int nt = 0; nt < 4; nt++)
            Y[((size_t)(b * SEQ + qrow)) * N_EMBD + h * HDIM + nt * 16 + l16] =
                f2bf(o[nt][r] * inv);
    }
}

// ---------------- launch ----------------
extern "C" void kernel_launch(void* const* d_in, const int* in_sizes, int n_in,
                              void* d_out, int out_size, void* d_ws, size_t ws_size,
                              hipStream_t stream) {
    const float* x       = (const float*)d_in[0];
    const float* age     = (const float*)d_in[1];
    const int*   mod_idx = (const int*)d_in[2];
    const float* mod_age = (const float*)d_in[3];
    const float* mod2    = (const float*)d_in[4];
    const float* mod3    = (const float*)d_in[5];
    const float* ln0w = (const float*)d_in[6],  *ln0b = (const float*)d_in[7];
    const float* ln1w = (const float*)d_in[8],  *ln1b = (const float*)d_in[9];
    const float* ln2w = (const float*)d_in[10], *ln2b = (const float*)d_in[11];
    const float* qb = (const float*)d_in[13];
    const float* kb = (const float*)d_in[15];
    const float* vb = (const float*)d_in[17];
    const float* cb = (const float*)d_in[19];
    const float* fcb = (const float*)d_in[21];
    const float* pb = (const float*)d_in[23];

    char* ws = (char*)d_ws;
    const size_t RB = (size_t)NROWS * N_EMBD * 2;   // 6.29 MB
    int* g   = (int*)ws;
    u16* wq  = (u16*)(ws + 32768);
    u16* wc  = wq + 3 * (size_t)W768;
    u16* wfc = wq + 4 * (size_t)W768;
    u16* wp  = wq + 4 * (size_t)W768 + WFC;
    size_t actoff = 32768 + 2 * (4 * (size_t)W768 + 2 * (size_t)WFC);
    char* act = ws + actoff;                        // 5 x RB contiguous
    u16* xn   = (u16*)(act);
    u16* sn   = (u16*)(act + RB);
    u16* qbuf = (u16*)(act + 2 * RB);
    u16* kbuf = (u16*)(act + 3 * RB);
    u16* vbuf = (u16*)(act + 4 * RB);
    float* x1 = (float*)(act + 5 * RB);
    u16* hbuf = (u16*)(act + 5 * RB + (size_t)NROWS * N_EMBD * 4);
    u16* yb = xn;
    // cproj partials: sn+qbuf span / kbuf+vbuf span (yb=xn still live)
    float* cpa = (float*)(act + RB);
    float* cpb = (float*)(act + 3 * RB);
    u16* hn = xn;                                   // ln2_fused output (xn free by then)
    // proj partials: xn+sn span / qbuf+kbuf span; p2 = d_out
    float* pp0 = (float*)(act);
    float* pp1 = (float*)(act + 2 * RB);

    prep_kernel<<<NCVT + 1024 + NBATCH, 256, 0, stream>>>(
        (const float*)d_in[12], (const float*)d_in[14], (const float*)d_in[16],
        (const float*)d_in[18], (const float*)d_in[20], (const float*)d_in[22], wq,
        x, ln1w, ln1b, xn, mod_idx, g);
    ln_rows<<<NROWS / 4, 256, 0, stream>>>(mod2, mod3, g, ln0w, ln0b, sn);

    gemm_qkv<<<dim3(N_EMBD / 128, NROWS / 64, 3), 256, 0, stream>>>(xn, sn, wq, qb, kb, vb, qbuf);

    attn_kernel<<<NBATCH * NHEAD * 16, 256, 0, stream>>>(qbuf, kbuf, vbuf, age, mod_age, yb);

    gemm_cproj_split<<<dim3(N_EMBD / 128, NROWS / 64, 2), 256, 0, stream>>>(yb, wc, cpa, cpb);
    ln2_fused<<<NROWS / 4, 256, 0, stream>>>(cpa, cpb, cb, x, ln2w, ln2b, x1, hn);
    gemm_fc<<<dim3(FFN / 128, NROWS / 64), 256, 0, stream>>>(hn, wfc, fcb, hbuf);
    gemm_proj_split<<<dim3(N_EMBD / 128, NROWS / 64, 3), 256, 0, stream>>>(hbuf, wp, pp0, pp1, (float*)d_out);
    reduce_proj<<<(NROWS * N_EMBD / 4) / 256, 256, 0, stream>>>(pp0, pp1, pb, x1, (float*)d_out);

    (void)in_sizes; (void)n_in; (void)out_size; (void)ws_size;
}

// Round 9
// 317.068 us; speedup vs baseline: 1.0398x; 1.0398x over previous
//
#include <hip/hip_runtime.h>

#define N_EMBD 768
#define SEQ    1024
#define NBATCH 4
#define NHEAD  12
#define HDIM   64
#define NROWS  4096   // B*L
#define FFN    3072
#define W768   589824    // 768*768
#define WFC    2359296   // 3072*768
#define NCVT   6912      // (4*W768 + 2*WFC) / 1024

typedef unsigned short u16;
typedef __bf16 bf16x8 __attribute__((ext_vector_type(8)));
typedef float  f32x4  __attribute__((ext_vector_type(4)));
typedef unsigned short u16x8 __attribute__((ext_vector_type(8)));

typedef const __attribute__((address_space(1))) unsigned int gu32;
typedef __attribute__((address_space(3))) unsigned int lu32;
#define GLL(g, l) __builtin_amdgcn_global_load_lds((gu32*)(g), (lu32*)(l), 16, 0, 0)

__device__ __forceinline__ u16 f2bf(float f) {
    union { float f; unsigned int i; } v; v.f = f;
    unsigned int r = v.i + 0x7fffu + ((v.i >> 16) & 1u);
    return (u16)(r >> 16);
}

// ---------------- prep: cvt_weights + ln1 + prefix ----------------
__global__ __launch_bounds__(256) void prep_kernel(const float* __restrict__ qw,
                                                   const float* __restrict__ kw,
                                                   const float* __restrict__ vw,
                                                   const float* __restrict__ cw,
                                                   const float* __restrict__ fcw,
                                                   const float* __restrict__ pw,
                                                   u16* __restrict__ wdst,
                                                   const float* __restrict__ x,
                                                   const float* __restrict__ ln1w,
                                                   const float* __restrict__ ln1b,
                                                   u16* __restrict__ xn,
                                                   const int* __restrict__ mod_idx,
                                                   int* __restrict__ g) {
    int bx = blockIdx.x;
    if (bx < NCVT) {
        size_t e = ((size_t)bx * 256 + threadIdx.x) * 4;
        const float* src; size_t base;
        if      (e < 1 * (size_t)W768) { src = qw;  base = 0; }
        else if (e < 2 * (size_t)W768) { src = kw;  base = 1 * (size_t)W768; }
        else if (e < 3 * (size_t)W768) { src = vw;  base = 2 * (size_t)W768; }
        else if (e < 4 * (size_t)W768) { src = cw;  base = 3 * (size_t)W768; }
        else if (e < 4 * (size_t)W768 + WFC) { src = fcw; base = 4 * (size_t)W768; }
        else { src = pw; base = 4 * (size_t)W768 + WFC; }
        float4 v = *(const float4*)(src + (e - base));
        ushort4 o;
        o.x = f2bf(v.x); o.y = f2bf(v.y); o.z = f2bf(v.z); o.w = f2bf(v.w);
        *(ushort4*)(wdst + e) = o;
    } else if (bx < NCVT + 1024) {
        int row  = (bx - NCVT) * 4 + (threadIdx.x >> 6);
        int lane = threadIdx.x & 63;
        const float* p = x + (size_t)row * N_EMBD;
        float vals[12];
        float s = 0.f, sq = 0.f;
#pragma unroll
        for (int c = 0; c < 12; c++) {
            float v = p[c * 64 + lane];
            vals[c] = v; s += v; sq += v * v;
        }
#pragma unroll
        for (int o = 32; o > 0; o >>= 1) { s += __shfl_xor(s, o); sq += __shfl_xor(sq, o); }
        float mean = s * (1.0f / 768.0f);
        float var  = sq * (1.0f / 768.0f) - mean * mean;
        float r    = rsqrtf(var + 1e-5f);
        u16* d = xn + (size_t)row * N_EMBD;
#pragma unroll
        for (int c = 0; c < 12; c++) {
            int idx = c * 64 + lane;
            d[idx] = f2bf((vals[c] - mean) * r * ln1w[idx] + ln1b[idx]);
        }
    } else {
        __shared__ int sc[256];
        int b = bx - NCVT - 1024;
        int j = threadIdx.x;
        int4 mi = *(const int4*)(mod_idx + b * SEQ + j * 4);
        int f0 = (mi.x == 2), f1 = (mi.y == 2), f2v = (mi.z == 2), f3 = (mi.w == 2);
        int t1 = f0 + f1, t2 = t1 + f2v, t3 = t2 + f3;
        sc[j] = t3;
        __syncthreads();
        for (int off = 1; off < 256; off <<= 1) {
            int add = (j >= off) ? sc[j - off] : 0;
            __syncthreads();
            sc[j] += add;
            __syncthreads();
        }
        int excl = sc[j] - t3;
        int cin[4] = {excl + f0, excl + t1, excl + t2, excl + t3};
        int fl[4] = {f0, f1, f2v, f3};
#pragma unroll
        for (int i2 = 0; i2 < 4; i2++) {
            int jj = j * 4 + i2;
            int occ = fl[i2] ? (cin[i2] - 1) : (jj - cin[i2]);
            occ = occ < 0 ? 0 : (occ > 511 ? 511 : occ);
            g[b * SEQ + jj] = fl[i2] ? (b * 512 + occ) : (2048 + b * 512 + occ);
        }
    }
}

// ---------------- LayerNorm (fp32 in, bf16 out), one wave per row ----------------
__global__ __launch_bounds__(256) void ln_rows(const float* __restrict__ src,
                                               const float* __restrict__ src2,
                                               const int* __restrict__ g,
                                               const float* __restrict__ w,
                                               const float* __restrict__ b,
                                               u16* __restrict__ dst) {
    int row  = blockIdx.x * 4 + (threadIdx.x >> 6);
    int lane = threadIdx.x & 63;
    const float* p;
    if (g) {
        int gi = g[row];
        p = (gi < 2048) ? (src + (size_t)gi * N_EMBD)
                        : (src2 + (size_t)(gi - 2048) * N_EMBD);
    } else {
        p = src + (size_t)row * N_EMBD;
    }
    float vals[12];
    float s = 0.f, sq = 0.f;
#pragma unroll
    for (int c = 0; c < 12; c++) {
        float v = p[c * 64 + lane];
        vals[c] = v; s += v; sq += v * v;
    }
#pragma unroll
    for (int o = 32; o > 0; o >>= 1) { s += __shfl_xor(s, o); sq += __shfl_xor(sq, o); }
    float mean = s * (1.0f / 768.0f);
    float var  = sq * (1.0f / 768.0f) - mean * mean;
    float r    = rsqrtf(var + 1e-5f);
    u16* d = dst + (size_t)row * N_EMBD;
#pragma unroll
    for (int c = 0; c < 12; c++) {
        int idx = c * 64 + lane;
        d[idx] = f2bf((vals[c] - mean) * r * w[idx] + b[idx]);
    }
}

// ---------------- fused: x1 = pa+pb+cb+x ; hn = LN(x1) ----------------
__global__ __launch_bounds__(256) void ln2_fused(const float* __restrict__ pa,
                                                 const float* __restrict__ pb,
                                                 const float* __restrict__ cb,
                                                 const float* __restrict__ x,
                                                 const float* __restrict__ ln2w,
                                                 const float* __restrict__ ln2b,
                                                 float* __restrict__ x1,
                                                 u16* __restrict__ hn) {
    int row  = blockIdx.x * 4 + (threadIdx.x >> 6);
    int lane = threadIdx.x & 63;
    size_t base = (size_t)row * N_EMBD;
    float vals[12];
    float s = 0.f, sq = 0.f;
#pragma unroll
    for (int c = 0; c < 12; c++) {
        int idx = c * 64 + lane;
        float v = pa[base + idx] + pb[base + idx] + cb[idx] + x[base + idx];
        vals[c] = v; s += v; sq += v * v;
        x1[base + idx] = v;
    }
#pragma unroll
    for (int o = 32; o > 0; o >>= 1) { s += __shfl_xor(s, o); sq += __shfl_xor(sq, o); }
    float mean = s * (1.0f / 768.0f);
    float var  = sq * (1.0f / 768.0f) - mean * mean;
    float r    = rsqrtf(var + 1e-5f);
    u16* d = hn + base;
#pragma unroll
    for (int c = 0; c < 12; c++) {
        int idx = c * 64 + lane;
        d[idx] = f2bf((vals[c] - mean) * r * ln2w[idx] + ln2b[idx]);
    }
}

// ---------------- GEMM cores: BK=32, GLL staging (round-5/7 verified shapes) ----
__device__ __forceinline__ void core128(const u16* __restrict__ A, const u16* __restrict__ W,
                                        int K, int m0, int n0, int t,
                                        u16* As, u16* Bs, f32x4 (&acc)[4][4]) {
    int w = t >> 6, lane = t & 63, quad = lane >> 4, l16 = lane & 15;
    int r16 = lane >> 2, c8 = (lane & 3) * 8;
    int wm = (w >> 1) * 64, wn = (w & 1) * 64;
    for (int k0 = 0; k0 < K; k0 += 32) {
        __syncthreads();
        const u16* ga = A + (size_t)(m0 + w * 32 + r16) * K + k0 + c8;
        const u16* gb = W + (size_t)(n0 + w * 32 + r16) * K + k0 + c8;
        GLL(ga,                  &As[(w * 32) * 32]);
        GLL(ga + 16 * (size_t)K, &As[(w * 32 + 16) * 32]);
        GLL(gb,                  &Bs[(w * 32) * 32]);
        GLL(gb + 16 * (size_t)K, &Bs[(w * 32 + 16) * 32]);
        __syncthreads();
        bf16x8 af[4], bfr[4];
#pragma unroll
        for (int i = 0; i < 4; i++)
            af[i] = *(const bf16x8*)&As[(wm + i * 16 + l16) * 32 + quad * 8];
#pragma unroll
        for (int j = 0; j < 4; j++)
            bfr[j] = *(const bf16x8*)&Bs[(wn + j * 16 + l16) * 32 + quad * 8];
#pragma unroll
        for (int i = 0; i < 4; i++)
#pragma unroll
            for (int j = 0; j < 4; j++)
                acc[i][j] = __builtin_amdgcn_mfma_f32_16x16x32_bf16(af[i], bfr[j], acc[i][j], 0, 0, 0);
    }
}

__device__ __forceinline__ void core64(const u16* __restrict__ A, const u16* __restrict__ W,
                                       int K, int kBeg, int kEnd, int m0, int n0, int t,
                                       u16* As, u16* Bs, f32x4 (&acc)[2][4]) {
    int w = t >> 6, lane = t & 63, quad = lane >> 4, l16 = lane & 15;
    int r16 = lane >> 2, c8 = (lane & 3) * 8;
    int wm = (w >> 1) * 32, wn = (w & 1) * 64;
    for (int k0 = kBeg; k0 < kEnd; k0 += 32) {
        __syncthreads();
        const u16* gb = W + (size_t)(n0 + w * 32 + r16) * K + k0 + c8;
        GLL(A + (size_t)(m0 + w * 16 + r16) * K + k0 + c8, &As[(w * 16) * 32]);
        GLL(gb,                  &Bs[(w * 32) * 32]);
        GLL(gb + 16 * (size_t)K, &Bs[(w * 32 + 16) * 32]);
        __syncthreads();
        bf16x8 af[2], bfr[4];
#pragma unroll
        for (int i = 0; i < 2; i++)
            af[i] = *(const bf16x8*)&As[(wm + i * 16 + l16) * 32 + quad * 8];
#pragma unroll
        for (int j = 0; j < 4; j++)
            bfr[j] = *(const bf16x8*)&Bs[(wn + j * 16 + l16) * 32 + quad * 8];
#pragma unroll
        for (int i = 0; i < 2; i++)
#pragma unroll
            for (int j = 0; j < 4; j++)
                acc[i][j] = __builtin_amdgcn_mfma_f32_16x16x32_bf16(af[i], bfr[j], acc[i][j], 0, 0, 0);
    }
}

// ---------------- QKV: 128x128 tiles, z in {0,1,2} ----------------
__global__ __launch_bounds__(256) void gemm_qkv(const u16* __restrict__ xn,
                                                const u16* __restrict__ sn,
                                                const u16* __restrict__ wq,
                                                const float* __restrict__ qb,
                                                const float* __restrict__ kb,
                                                const float* __restrict__ vb,
                                                u16* __restrict__ outbase) {
    __shared__ u16 As[128 * 32], Bs[128 * 32];
    int z = blockIdx.z;
    const u16* A = (z == 0) ? xn : sn;
    const u16* W = wq + (size_t)z * W768;
    const float* bias = (z == 0) ? qb : ((z == 1) ? kb : vb);
    u16* C = outbase + (size_t)z * ((size_t)NROWS * N_EMBD);
    int m0 = blockIdx.y * 128, n0 = blockIdx.x * 128;
    int t = threadIdx.x;
    f32x4 acc[4][4];
#pragma unroll
    for (int i = 0; i < 4; i++)
#pragma unroll
        for (int j = 0; j < 4; j++) acc[i][j] = (f32x4){0.f, 0.f, 0.f, 0.f};
    core128(A, W, N_EMBD, m0, n0, t, As, Bs, acc);
    int w = t >> 6, lane = t & 63, quad = lane >> 4, l16 = lane & 15;
    int wm = (w >> 1) * 64, wn = (w & 1) * 64;
#pragma unroll
    for (int j = 0; j < 4; j++) {
        int col = n0 + wn + j * 16 + l16;
        float bv = bias[col];
#pragma unroll
        for (int i = 0; i < 4; i++) {
            int rowb = m0 + wm + i * 16 + quad * 4;
#pragma unroll
            for (int r = 0; r < 4; r++)
                C[(size_t)(rowb + r) * N_EMBD + col] = f2bf(acc[i][j][r] + bv);
        }
    }
}

// ---------------- fc: 128x128 tiles, K=768, fast GELU, bf16 out ----------------
__global__ __launch_bounds__(256) void gemm_fc(const u16* __restrict__ A,
                                               const u16* __restrict__ W,
                                               const float* __restrict__ bias,
                                               u16* __restrict__ C) {
    __shared__ u16 As[128 * 32], Bs[128 * 32];
    int m0 = blockIdx.y * 128, n0 = blockIdx.x * 128;
    int t = threadIdx.x;
    f32x4 acc[4][4];
#pragma unroll
    for (int i = 0; i < 4; i++)
#pragma unroll
        for (int j = 0; j < 4; j++) acc[i][j] = (f32x4){0.f, 0.f, 0.f, 0.f};
    core128(A, W, N_EMBD, m0, n0, t, As, Bs, acc);
    int w = t >> 6, lane = t & 63, quad = lane >> 4, l16 = lane & 15;
    int wm = (w >> 1) * 64, wn = (w & 1) * 64;
#pragma unroll
    for (int j = 0; j < 4; j++) {
        int col = n0 + wn + j * 16 + l16;
        float bv = bias[col];
#pragma unroll
        for (int i = 0; i < 4; i++) {
            int rowb = m0 + wm + i * 16 + quad * 4;
#pragma unroll
            for (int r = 0; r < 4; r++) {
                float v = acc[i][j][r] + bv;
                float y = v * (1.595769122f + 0.071354816f * v * v);
                float gel = v / (1.0f + __expf(-y));
                C[(size_t)(rowb + r) * FFN + col] = f2bf(gel);
            }
        }
    }
}

// ---------------- c-proj: 64x128, K=768 split-K x2, raw fp32 partials ----------
__global__ __launch_bounds__(256) void gemm_cproj_split(const u16* __restrict__ A,
                                                        const u16* __restrict__ W,
                                                        float* __restrict__ pa,
                                                        float* __restrict__ pb) {
    __shared__ u16 As[64 * 32], Bs[128 * 32];
    int z = blockIdx.z;
    float* P = z ? pb : pa;
    int m0 = blockIdx.y * 64, n0 = blockIdx.x * 128;
    int t = threadIdx.x;
    f32x4 acc[2][4];
#pragma unroll
    for (int i = 0; i < 2; i++)
#pragma unroll
        for (int j = 0; j < 4; j++) acc[i][j] = (f32x4){0.f, 0.f, 0.f, 0.f};
    core64(A, W, N_EMBD, z * 384, (z + 1) * 384, m0, n0, t, As, Bs, acc);
    int w = t >> 6, lane = t & 63, quad = lane >> 4, l16 = lane & 15;
    int wm = (w >> 1) * 32, wn = (w & 1) * 64;
#pragma unroll
    for (int j = 0; j < 4; j++) {
        int col = n0 + wn + j * 16 + l16;
#pragma unroll
        for (int i = 0; i < 2; i++) {
            int rowb = m0 + wm + i * 16 + quad * 4;
#pragma unroll
            for (int r = 0; r < 4; r++)
                P[(size_t)(rowb + r) * N_EMBD + col] = acc[i][j][r];
        }
    }
}

// ---------------- proj: 64x128, K=3072 split-K x3, fp32 partials ----------
__global__ __launch_bounds__(256) void gemm_proj_split(const u16* __restrict__ A,
                                                       const u16* __restrict__ W,
                                                       float* __restrict__ p0,
                                                       float* __restrict__ p1,
                                                       float* __restrict__ p2) {
    __shared__ u16 As[64 * 32], Bs[128 * 32];
    int z = blockIdx.z;
    float* P = (z == 0) ? p0 : ((z == 1) ? p1 : p2);
    int m0 = blockIdx.y * 64, n0 = blockIdx.x * 128;
    int t = threadIdx.x;
    f32x4 acc[2][4];
#pragma unroll
    for (int i = 0; i < 2; i++)
#pragma unroll
        for (int j = 0; j < 4; j++) acc[i][j] = (f32x4){0.f, 0.f, 0.f, 0.f};
    core64(A, W, FFN, z * 1024, (z + 1) * 1024, m0, n0, t, As, Bs, acc);
    int w = t >> 6, lane = t & 63, quad = lane >> 4, l16 = lane & 15;
    int wm = (w >> 1) * 32, wn = (w & 1) * 64;
#pragma unroll
    for (int j = 0; j < 4; j++) {
        int col = n0 + wn + j * 16 + l16;
#pragma unroll
        for (int i = 0; i < 2; i++) {
            int rowb = m0 + wm + i * 16 + quad * 4;
#pragma unroll
            for (int r = 0; r < 4; r++)
                P[(size_t)(rowb + r) * N_EMBD + col] = acc[i][j][r];
        }
    }
}

// out = p0 + p1 + out(=p2) + bias[col] + x1
__global__ __launch_bounds__(256) void reduce_proj(const float* __restrict__ p0,
                                                   const float* __restrict__ p1,
                                                   const float* __restrict__ bias,
                                                   const float* __restrict__ x1,
                                                   float* __restrict__ out) {
    size_t idx = ((size_t)blockIdx.x * 256 + threadIdx.x) * 4;
    int col = (int)(idx % N_EMBD);
    float4 a = *(const float4*)(p0 + idx);
    float4 b = *(const float4*)(p1 + idx);
    float4 c = *(const float4*)(out + idx);
    float4 r = *(const float4*)(x1 + idx);
    float4 bb = *(const float4*)(bias + col);
    float4 o;
    o.x = a.x + b.x + c.x + r.x + bb.x;
    o.y = a.y + b.y + c.y + r.y + bb.y;
    o.z = a.z + b.z + c.z + r.z + bb.z;
    o.w = a.w + b.w + c.w + r.w + bb.w;
    *(float4*)(out + idx) = o;
}

// ---------------- flash cross-attention (round-5 verified) ----------------
#define KST 72

__global__ __launch_bounds__(256) void attn_kernel(const u16* __restrict__ Q,
                                                   const u16* __restrict__ K,
                                                   const u16* __restrict__ V,
                                                   const float* __restrict__ age,
                                                   const float* __restrict__ mod_age,
                                                   u16* __restrict__ Y) {
    __shared__ u16 Kl[64 * KST];
    __shared__ u16 Vt[64 * KST];
    __shared__ u16 Pl[4][16 * KST];

    int bx = blockIdx.x;
    int qt = 15 - (bx / 48);
    int bh = bx % 48;
    int b = bh / NHEAD, h = bh % NHEAD;
    int t = threadIdx.x;
    int w = t >> 6, lane = t & 63, quad = lane >> 4, l16 = lane & 15;
    int q0 = qt * 64 + w * 16;

    size_t qrowbase = ((size_t)(b * SEQ + q0 + l16)) * N_EMBD + h * HDIM;
    bf16x8 qf0 = *(const bf16x8*)&Q[qrowbase + quad * 8];
    bf16x8 qf1 = *(const bf16x8*)&Q[qrowbase + 32 + quad * 8];

    float age_r[4];
#pragma unroll
    for (int r = 0; r < 4; r++) age_r[r] = age[b * SEQ + q0 + quad * 4 + r];
    float age_q0      = __shfl(age_r[0], 0);
    float age_max_blk = age[b * SEQ + qt * 64 + 63];
    float mod_min     = mod_age[b * SEQ];

    float mv0 = (lane < 16) ? mod_age[b * SEQ + lane * 64] : 1e30f;
    unsigned long long bm = __ballot(mv0 > age_max_blk);
    int nkt = bm ? (__ffsll(bm) - 1) : 16;

    int krow0 = t >> 3,        kc8 = (t & 7) * 8;
    int krow1 = 32 + (t >> 3);
    int vrow  = t & 63;
    int vc8_0 = t >> 6, vc8_1 = 4 + (t >> 6);

    float m_i[4] = {-1e30f, -1e30f, -1e30f, -1e30f};
    float l_i[4] = {0.f, 0.f, 0.f, 0.f};
    f32x4 o[4];
#pragma unroll
    for (int nt = 0; nt < 4; nt++) o[nt] = (f32x4){0.f, 0.f, 0.f, 0.f};

    u16x8 kr0, kr1, vr0, vr1;
    float mreg = 0.f;
    if (nkt > 0) {
        size_t kb = ((size_t)(b * SEQ)) * N_EMBD + h * HDIM;
        kr0 = *(const u16x8*)(K + kb + (size_t)krow0 * N_EMBD + kc8);
        kr1 = *(const u16x8*)(K + kb + (size_t)krow1 * N_EMBD + kc8);
        vr0 = *(const u16x8*)(V + kb + (size_t)vrow * N_EMBD + vc8_0 * 8);
        vr1 = *(const u16x8*)(V + kb + (size_t)vrow * N_EMBD + vc8_1 * 8);
        mreg = mod_age[b * SEQ + lane];
    }

    for (int kt = 0; kt < nkt; kt++) {
        __syncthreads();
        *(u16x8*)&Kl[krow0 * KST + kc8] = kr0;
        *(u16x8*)&Kl[krow1 * KST + kc8] = kr1;
#pragma unroll
        for (int e = 0; e < 8; e++) Vt[(vc8_0 * 8 + e) * KST + vrow] = vr0[e];
#pragma unroll
        for (int e = 0; e < 8; e++) Vt[(vc8_1 * 8 + e) * KST + vrow] = vr1[e];
        float mcur = mreg;
        __syncthreads();

        if (kt + 1 < nkt) {
            size_t kb = ((size_t)(b * SEQ + (kt + 1) * 64)) * N_EMBD + h * HDIM;
            kr0 = *(const u16x8*)(K + kb + (size_t)krow0 * N_EMBD + kc8);
            kr1 = *(const u16x8*)(K + kb + (size_t)krow1 * N_EMBD + kc8);
            vr0 = *(const u16x8*)(V + kb + (size_t)vrow * N_EMBD + vc8_0 * 8);
            vr1 = *(const u16x8*)(V + kb + (size_t)vrow * N_EMBD + vc8_1 * 8);
            mreg = mod_age[b * SEQ + (kt + 1) * 64 + lane];
        }

        float tile_max = __shfl(mcur, 63);
        bool need_mask = tile_max > age_q0;
        float p[4][4];
#pragma unroll
        for (int jt = 0; jt < 4; jt++) {
            f32x4 s = (f32x4){0.f, 0.f, 0.f, 0.f};
            bf16x8 kf0 = *(const bf16x8*)&Kl[(jt * 16 + l16) * KST + quad * 8];
            bf16x8 kf1 = *(const bf16x8*)&Kl[(jt * 16 + l16) * KST + 32 + quad * 8];
            s = __builtin_amdgcn_mfma_f32_16x16x32_bf16(qf0, kf0, s, 0, 0, 0);
            s = __builtin_amdgcn_mfma_f32_16x16x32_bf16(qf1, kf1, s, 0, 0, 0);
            float mval = __shfl(mcur, jt * 16 + l16);
#pragma unroll
            for (int r = 0; r < 4; r++) {
                float sv = s[r] * 0.125f;
                p[jt][r] = (!need_mask || mval <= age_r[r]) ? sv : -1e30f;
            }
        }
        float alpha[4];
#pragma unroll
        for (int r = 0; r < 4; r++) {
            float mx = fmaxf(fmaxf(p[0][r], p[1][r]), fmaxf(p[2][r], p[3][r]));
#pragma unroll
            for (int msk = 1; msk < 16; msk <<= 1) mx = fmaxf(mx, __shfl_xor(mx, msk));
            float mnew = fmaxf(m_i[r], mx);
            alpha[r] = __expf(m_i[r] - mnew);
            float srow = 0.f;
#pragma unroll
            for (int jt = 0; jt < 4; jt++) {
                float pv = __expf(p[jt][r] - mnew);
                p[jt][r] = pv;
                srow += pv;
            }
#pragma unroll
            for (int msk = 1; msk < 16; msk <<= 1) srow += __shfl_xor(srow, msk);
            l_i[r] = l_i[r] * alpha[r] + srow;
            m_i[r] = mnew;
        }
#pragma unroll
        for (int jt = 0; jt < 4; jt++)
#pragma unroll
            for (int r = 0; r < 4; r++)
                Pl[w][(quad * 4 + r) * KST + jt * 16 + l16] = f2bf(p[jt][r]);
#pragma unroll
        for (int nt = 0; nt < 4; nt++)
#pragma unroll
            for (int r = 0; r < 4; r++) o[nt][r] *= alpha[r];
#pragma unroll
        for (int c = 0; c < 2; c++) {
            bf16x8 pf = *(const bf16x8*)&Pl[w][l16 * KST + c * 32 + quad * 8];
#pragma unroll
            for (int nt = 0; nt < 4; nt++) {
                bf16x8 vf = *(const bf16x8*)&Vt[(nt * 16 + l16) * KST + c * 32 + quad * 8];
                o[nt] = __builtin_amdgcn_mfma_f32_16x16x32_bf16(pf, vf, o[nt], 0, 0, 0);
            }
        }
    }
#pragma unroll
    for (int r = 0; r < 4; r++) {
        int qrow = q0 + quad * 4 + r;
        float inv = (age_r[r] >= mod_min) ? (1.0f / l_i[r]) : 0.0f;
#pragma unroll
        for (int nt = 0; nt < 4; nt++)
            Y[((size_t)(b * SEQ + qrow)) * N_EMBD + h * HDIM + nt * 16 + l16] =
                f2bf(o[nt][r] * inv);
    }
}

// ---------------- launch ----------------
extern "C" void kernel_launch(void* const* d_in, const int* in_sizes, int n_in,
                              void* d_out, int out_size, void* d_ws, size_t ws_size,
                              hipStream_t stream) {
    const float* x       = (const float*)d_in[0];
    const float* age     = (const float*)d_in[1];
    const int*   mod_idx = (const int*)d_in[2];
    const float* mod_age = (const float*)d_in[3];
    const float* mod2    = (const float*)d_in[4];
    const float* mod3    = (const float*)d_in[5];
    const float* ln0w = (const float*)d_in[6],  *ln0b = (const float*)d_in[7];
    const float* ln1w = (const float*)d_in[8],  *ln1b = (const float*)d_in[9];
    const float* ln2w = (const float*)d_in[10], *ln2b = (const float*)d_in[11];
    const float* qb = (const float*)d_in[13];
    const float* kb = (const float*)d_in[15];
    const float* vb = (const float*)d_in[17];
    const float* cb = (const float*)d_in[19];
    const float* fcb = (const float*)d_in[21];
    const float* pb = (const float*)d_in[23];

    char* ws = (char*)d_ws;
    const size_t RB = (size_t)NROWS * N_EMBD * 2;   // 6.29 MB
    int* g   = (int*)ws;
    u16* wq  = (u16*)(ws + 32768);
    u16* wc  = wq + 3 * (size_t)W768;
    u16* wfc = wq + 4 * (size_t)W768;
    u16* wp  = wq + 4 * (size_t)W768 + WFC;
    size_t actoff = 32768 + 2 * (4 * (size_t)W768 + 2 * (size_t)WFC);
    char* act = ws + actoff;                        // 5 x RB contiguous
    u16* xn   = (u16*)(act);
    u16* sn   = (u16*)(act + RB);
    u16* qbuf = (u16*)(act + 2 * RB);
    u16* kbuf = (u16*)(act + 3 * RB);
    u16* vbuf = (u16*)(act + 4 * RB);
    float* x1 = (float*)(act + 5 * RB);
    u16* hbuf = (u16*)(act + 5 * RB + (size_t)NROWS * N_EMBD * 4);
    u16* yb = xn;
    float* cpa = (float*)(act + RB);       // cproj partial A (spans sn+qbuf)
    float* cpb = (float*)(act + 3 * RB);   // cproj partial B (spans kbuf+vbuf)
    u16* hn = xn;                          // ln2_fused bf16 out (xn free by then)
    float* pp0 = (float*)(act);            // proj partial 0 (spans xn+sn)
    float* pp1 = (float*)(act + 2 * RB);   // proj partial 1 (spans qbuf+kbuf)

    prep_kernel<<<NCVT + 1024 + NBATCH, 256, 0, stream>>>(
        (const float*)d_in[12], (const float*)d_in[14], (const float*)d_in[16],
        (const float*)d_in[18], (const float*)d_in[20], (const float*)d_in[22], wq,
        x, ln1w, ln1b, xn, mod_idx, g);
    ln_rows<<<NROWS / 4, 256, 0, stream>>>(mod2, mod3, g, ln0w, ln0b, sn);

    gemm_qkv<<<dim3(N_EMBD / 128, NROWS / 128, 3), 256, 0, stream>>>(xn, sn, wq, qb, kb, vb, qbuf);

    attn_kernel<<<NBATCH * NHEAD * 16, 256, 0, stream>>>(qbuf, kbuf, vbuf, age, mod_age, yb);

    gemm_cproj_split<<<dim3(N_EMBD / 128, NROWS / 64, 2), 256, 0, stream>>>(yb, wc, cpa, cpb);
    ln2_fused<<<NROWS / 4, 256, 0, stream>>>(cpa, cpb, cb, x, ln2w, ln2b, x1, hn);
    gemm_fc<<<dim3(FFN / 128, NROWS / 128), 256, 0, stream>>>(hn, wfc, fcb, hbuf);
    gemm_proj_split<<<dim3(N_EMBD / 128, NROWS / 64, 3), 256, 0, stream>>>(hbuf, wp, pp0, pp1, (float*)d_out);
    reduce_proj<<<(NROWS * N_EMBD / 4) / 256, 256, 0, stream>>>(pp0, pp1, pb, x1, (float*)d_out);

    (void)in_sizes; (void)n_in; (void)out_size; (void)ws_size;
}

// Round 10
// 299.445 us; speedup vs baseline: 1.1010x; 1.0589x over previous
//
#include <hip/hip_runtime.h>

#define N_EMBD 768
#define SEQ    1024
#define NBATCH 4
#define NHEAD  12
#define HDIM   64
#define NROWS  4096   // B*L
#define FFN    3072
#define W768   589824    // 768*768
#define WFC    2359296   // 3072*768
#define NCVT   6912      // (4*W768 + 2*WFC) / 1024

typedef unsigned short u16;
typedef __bf16 bf16x8 __attribute__((ext_vector_type(8)));
typedef float  f32x4  __attribute__((ext_vector_type(4)));
typedef unsigned short u16x8 __attribute__((ext_vector_type(8)));

typedef const __attribute__((address_space(1))) unsigned int gu32;
typedef __attribute__((address_space(3))) unsigned int lu32;
#define GLL(g, l) __builtin_amdgcn_global_load_lds((gu32*)(g), (lu32*)(l), 16, 0, 0)

__device__ __forceinline__ u16 f2bf(float f) {
    union { float f; unsigned int i; } v; v.f = f;
    unsigned int r = v.i + 0x7fffu + ((v.i >> 16) & 1u);
    return (u16)(r >> 16);
}

// ---------------- prep: cvt_weights + ln1 + prefix ----------------
__global__ __launch_bounds__(256) void prep_kernel(const float* __restrict__ qw,
                                                   const float* __restrict__ kw,
                                                   const float* __restrict__ vw,
                                                   const float* __restrict__ cw,
                                                   const float* __restrict__ fcw,
                                                   const float* __restrict__ pw,
                                                   u16* __restrict__ wdst,
                                                   const float* __restrict__ x,
                                                   const float* __restrict__ ln1w,
                                                   const float* __restrict__ ln1b,
                                                   u16* __restrict__ xn,
                                                   const int* __restrict__ mod_idx,
                                                   int* __restrict__ g) {
    int bx = blockIdx.x;
    if (bx < NCVT) {
        size_t e = ((size_t)bx * 256 + threadIdx.x) * 4;
        const float* src; size_t base;
        if      (e < 1 * (size_t)W768) { src = qw;  base = 0; }
        else if (e < 2 * (size_t)W768) { src = kw;  base = 1 * (size_t)W768; }
        else if (e < 3 * (size_t)W768) { src = vw;  base = 2 * (size_t)W768; }
        else if (e < 4 * (size_t)W768) { src = cw;  base = 3 * (size_t)W768; }
        else if (e < 4 * (size_t)W768 + WFC) { src = fcw; base = 4 * (size_t)W768; }
        else { src = pw; base = 4 * (size_t)W768 + WFC; }
        float4 v = *(const float4*)(src + (e - base));
        ushort4 o;
        o.x = f2bf(v.x); o.y = f2bf(v.y); o.z = f2bf(v.z); o.w = f2bf(v.w);
        *(ushort4*)(wdst + e) = o;
    } else if (bx < NCVT + 1024) {
        int row  = (bx - NCVT) * 4 + (threadIdx.x >> 6);
        int lane = threadIdx.x & 63;
        const float* p = x + (size_t)row * N_EMBD;
        float vals[12];
        float s = 0.f, sq = 0.f;
#pragma unroll
        for (int c = 0; c < 12; c++) {
            float v = p[c * 64 + lane];
            vals[c] = v; s += v; sq += v * v;
        }
#pragma unroll
        for (int o = 32; o > 0; o >>= 1) { s += __shfl_xor(s, o); sq += __shfl_xor(sq, o); }
        float mean = s * (1.0f / 768.0f);
        float var  = sq * (1.0f / 768.0f) - mean * mean;
        float r    = rsqrtf(var + 1e-5f);
        u16* d = xn + (size_t)row * N_EMBD;
#pragma unroll
        for (int c = 0; c < 12; c++) {
            int idx = c * 64 + lane;
            d[idx] = f2bf((vals[c] - mean) * r * ln1w[idx] + ln1b[idx]);
        }
    } else {
        __shared__ int sc[256];
        int b = bx - NCVT - 1024;
        int j = threadIdx.x;
        int4 mi = *(const int4*)(mod_idx + b * SEQ + j * 4);
        int f0 = (mi.x == 2), f1 = (mi.y == 2), f2v = (mi.z == 2), f3 = (mi.w == 2);
        int t1 = f0 + f1, t2 = t1 + f2v, t3 = t2 + f3;
        sc[j] = t3;
        __syncthreads();
        for (int off = 1; off < 256; off <<= 1) {
            int add = (j >= off) ? sc[j - off] : 0;
            __syncthreads();
            sc[j] += add;
            __syncthreads();
        }
        int excl = sc[j] - t3;
        int cin[4] = {excl + f0, excl + t1, excl + t2, excl + t3};
        int fl[4] = {f0, f1, f2v, f3};
#pragma unroll
        for (int i2 = 0; i2 < 4; i2++) {
            int jj = j * 4 + i2;
            int occ = fl[i2] ? (cin[i2] - 1) : (jj - cin[i2]);
            occ = occ < 0 ? 0 : (occ > 511 ? 511 : occ);
            g[b * SEQ + jj] = fl[i2] ? (b * 512 + occ) : (2048 + b * 512 + occ);
        }
    }
}

// ---------------- LayerNorm (fp32 in, bf16 out), one wave per row ----------------
__global__ __launch_bounds__(256) void ln_rows(const float* __restrict__ src,
                                               const float* __restrict__ src2,
                                               const int* __restrict__ g,
                                               const float* __restrict__ w,
                                               const float* __restrict__ b,
                                               u16* __restrict__ dst) {
    int row  = blockIdx.x * 4 + (threadIdx.x >> 6);
    int lane = threadIdx.x & 63;
    const float* p;
    if (g) {
        int gi = g[row];
        p = (gi < 2048) ? (src + (size_t)gi * N_EMBD)
                        : (src2 + (size_t)(gi - 2048) * N_EMBD);
    } else {
        p = src + (size_t)row * N_EMBD;
    }
    float vals[12];
    float s = 0.f, sq = 0.f;
#pragma unroll
    for (int c = 0; c < 12; c++) {
        float v = p[c * 64 + lane];
        vals[c] = v; s += v; sq += v * v;
    }
#pragma unroll
    for (int o = 32; o > 0; o >>= 1) { s += __shfl_xor(s, o); sq += __shfl_xor(sq, o); }
    float mean = s * (1.0f / 768.0f);
    float var  = sq * (1.0f / 768.0f) - mean * mean;
    float r    = rsqrtf(var + 1e-5f);
    u16* d = dst + (size_t)row * N_EMBD;
#pragma unroll
    for (int c = 0; c < 12; c++) {
        int idx = c * 64 + lane;
        d[idx] = f2bf((vals[c] - mean) * r * w[idx] + b[idx]);
    }
}

// ---------------- GEMM cores: BK=32, GLL staging (round-5/7 verified shapes) ----
__device__ __forceinline__ void core128(const u16* __restrict__ A, const u16* __restrict__ W,
                                        int K, int m0, int n0, int t,
                                        u16* As, u16* Bs, f32x4 (&acc)[4][4]) {
    int w = t >> 6, lane = t & 63, quad = lane >> 4, l16 = lane & 15;
    int r16 = lane >> 2, c8 = (lane & 3) * 8;
    int wm = (w >> 1) * 64, wn = (w & 1) * 64;
    for (int k0 = 0; k0 < K; k0 += 32) {
        __syncthreads();
        const u16* ga = A + (size_t)(m0 + w * 32 + r16) * K + k0 + c8;
        const u16* gb = W + (size_t)(n0 + w * 32 + r16) * K + k0 + c8;
        GLL(ga,                  &As[(w * 32) * 32]);
        GLL(ga + 16 * (size_t)K, &As[(w * 32 + 16) * 32]);
        GLL(gb,                  &Bs[(w * 32) * 32]);
        GLL(gb + 16 * (size_t)K, &Bs[(w * 32 + 16) * 32]);
        __syncthreads();
        bf16x8 af[4], bfr[4];
#pragma unroll
        for (int i = 0; i < 4; i++)
            af[i] = *(const bf16x8*)&As[(wm + i * 16 + l16) * 32 + quad * 8];
#pragma unroll
        for (int j = 0; j < 4; j++)
            bfr[j] = *(const bf16x8*)&Bs[(wn + j * 16 + l16) * 32 + quad * 8];
#pragma unroll
        for (int i = 0; i < 4; i++)
#pragma unroll
            for (int j = 0; j < 4; j++)
                acc[i][j] = __builtin_amdgcn_mfma_f32_16x16x32_bf16(af[i], bfr[j], acc[i][j], 0, 0, 0);
    }
}

__device__ __forceinline__ void core64(const u16* __restrict__ A, const u16* __restrict__ W,
                                       int K, int kBeg, int kEnd, int m0, int n0, int t,
                                       u16* As, u16* Bs, f32x4 (&acc)[2][4]) {
    int w = t >> 6, lane = t & 63, quad = lane >> 4, l16 = lane & 15;
    int r16 = lane >> 2, c8 = (lane & 3) * 8;
    int wm = (w >> 1) * 32, wn = (w & 1) * 64;
    for (int k0 = kBeg; k0 < kEnd; k0 += 32) {
        __syncthreads();
        const u16* gb = W + (size_t)(n0 + w * 32 + r16) * K + k0 + c8;
        GLL(A + (size_t)(m0 + w * 16 + r16) * K + k0 + c8, &As[(w * 16) * 32]);
        GLL(gb,                  &Bs[(w * 32) * 32]);
        GLL(gb + 16 * (size_t)K, &Bs[(w * 32 + 16) * 32]);
        __syncthreads();
        bf16x8 af[2], bfr[4];
#pragma unroll
        for (int i = 0; i < 2; i++)
            af[i] = *(const bf16x8*)&As[(wm + i * 16 + l16) * 32 + quad * 8];
#pragma unroll
        for (int j = 0; j < 4; j++)
            bfr[j] = *(const bf16x8*)&Bs[(wn + j * 16 + l16) * 32 + quad * 8];
#pragma unroll
        for (int i = 0; i < 2; i++)
#pragma unroll
            for (int j = 0; j < 4; j++)
                acc[i][j] = __builtin_amdgcn_mfma_f32_16x16x32_bf16(af[i], bfr[j], acc[i][j], 0, 0, 0);
    }
}

// ---------------- QKV: 128x128, 1D grid 576, XCD swizzle (same m -> same XCD) ----
__global__ __launch_bounds__(256) void gemm_qkv(const u16* __restrict__ xn,
                                                const u16* __restrict__ sn,
                                                const u16* __restrict__ wq,
                                                const float* __restrict__ qb,
                                                const float* __restrict__ kb,
                                                const float* __restrict__ vb,
                                                u16* __restrict__ outbase) {
    __shared__ u16 As[128 * 32], Bs[128 * 32];
    int bxg = blockIdx.x;
    int c = bxg & 7, s = bxg >> 3;          // s in [0,72)
    int mg = s / 18, r = s % 18;
    int z = r / 6, n = r % 6;
    int m0 = (mg * 8 + c) * 128, n0 = n * 128;
    const u16* A = (z == 0) ? xn : sn;
    const u16* W = wq + (size_t)z * W768;
    const float* bias = (z == 0) ? qb : ((z == 1) ? kb : vb);
    u16* C = outbase + (size_t)z * ((size_t)NROWS * N_EMBD);
    int t = threadIdx.x;
    f32x4 acc[4][4];
#pragma unroll
    for (int i = 0; i < 4; i++)
#pragma unroll
        for (int j = 0; j < 4; j++) acc[i][j] = (f32x4){0.f, 0.f, 0.f, 0.f};
    core128(A, W, N_EMBD, m0, n0, t, As, Bs, acc);
    int w = t >> 6, lane = t & 63, quad = lane >> 4, l16 = lane & 15;
    int wm = (w >> 1) * 64, wn = (w & 1) * 64;
#pragma unroll
    for (int j = 0; j < 4; j++) {
        int col = n0 + wn + j * 16 + l16;
        float bv = bias[col];
#pragma unroll
        for (int i = 0; i < 4; i++) {
            int rowb = m0 + wm + i * 16 + quad * 4;
#pragma unroll
            for (int r2 = 0; r2 < 4; r2++)
                C[(size_t)(rowb + r2) * N_EMBD + col] = f2bf(acc[i][j][r2] + bv);
        }
    }
}

// ---------------- fc: 128x128, 1D grid 768, XCD swizzle, fast GELU ----------------
__global__ __launch_bounds__(256) void gemm_fc(const u16* __restrict__ A,
                                               const u16* __restrict__ W,
                                               const float* __restrict__ bias,
                                               u16* __restrict__ C) {
    __shared__ u16 As[128 * 32], Bs[128 * 32];
    int bxg = blockIdx.x;
    int c = bxg & 7, s = bxg >> 3;          // s in [0,96)
    int mg = s / 24, n = s % 24;
    int m0 = (mg * 8 + c) * 128, n0 = n * 128;
    int t = threadIdx.x;
    f32x4 acc[4][4];
#pragma unroll
    for (int i = 0; i < 4; i++)
#pragma unroll
        for (int j = 0; j < 4; j++) acc[i][j] = (f32x4){0.f, 0.f, 0.f, 0.f};
    core128(A, W, N_EMBD, m0, n0, t, As, Bs, acc);
    int w = t >> 6, lane = t & 63, quad = lane >> 4, l16 = lane & 15;
    int wm = (w >> 1) * 64, wn = (w & 1) * 64;
#pragma unroll
    for (int j = 0; j < 4; j++) {
        int col = n0 + wn + j * 16 + l16;
        float bv = bias[col];
#pragma unroll
        for (int i = 0; i < 4; i++) {
            int rowb = m0 + wm + i * 16 + quad * 4;
#pragma unroll
            for (int r = 0; r < 4; r++) {
                float v = acc[i][j][r] + bv;
                float y = v * (1.595769122f + 0.071354816f * v * v);
                float gel = v / (1.0f + __expf(-y));
                C[(size_t)(rowb + r) * FFN + col] = f2bf(gel);
            }
        }
    }
}

// ---------------- c-proj: 64x128 tile, K=768, out fp32 = acc + bias + x ----------
__global__ __launch_bounds__(256) void gemm_cproj(const u16* __restrict__ A,
                                                  const u16* __restrict__ W,
                                                  const float* __restrict__ bias,
                                                  const float* __restrict__ Res,
                                                  float* __restrict__ C) {
    __shared__ u16 As[64 * 32], Bs[128 * 32];
    int m0 = blockIdx.y * 64, n0 = blockIdx.x * 128;
    int t = threadIdx.x;
    f32x4 acc[2][4];
#pragma unroll
    for (int i = 0; i < 2; i++)
#pragma unroll
        for (int j = 0; j < 4; j++) acc[i][j] = (f32x4){0.f, 0.f, 0.f, 0.f};
    core64(A, W, N_EMBD, 0, N_EMBD, m0, n0, t, As, Bs, acc);
    int w = t >> 6, lane = t & 63, quad = lane >> 4, l16 = lane & 15;
    int wm = (w >> 1) * 32, wn = (w & 1) * 64;
#pragma unroll
    for (int j = 0; j < 4; j++) {
        int col = n0 + wn + j * 16 + l16;
        float bv = bias[col];
#pragma unroll
        for (int i = 0; i < 2; i++) {
            int rowb = m0 + wm + i * 16 + quad * 4;
#pragma unroll
            for (int r = 0; r < 4; r++) {
                size_t idx = (size_t)(rowb + r) * N_EMBD + col;
                C[idx] = acc[i][j][r] + bv + Res[idx];
            }
        }
    }
}

// ---------------- proj: 64x128, K=3072 split-K x2, 1D grid 768, XCD swizzle ------
__global__ __launch_bounds__(256) void gemm_proj_split(const u16* __restrict__ A,
                                                       const u16* __restrict__ W,
                                                       float* __restrict__ p0,
                                                       float* __restrict__ p1) {
    __shared__ u16 As[64 * 32], Bs[128 * 32];
    int bxg = blockIdx.x;
    int c = bxg & 7, s = bxg >> 3;          // s in [0,96)
    int mg = s / 12, r = s % 12;
    int z = r / 6, n = r % 6;
    int m0 = (mg * 8 + c) * 64, n0 = n * 128;
    float* P = z ? p1 : p0;
    int t = threadIdx.x;
    f32x4 acc[2][4];
#pragma unroll
    for (int i = 0; i < 2; i++)
#pragma unroll
        for (int j = 0; j < 4; j++) acc[i][j] = (f32x4){0.f, 0.f, 0.f, 0.f};
    core64(A, W, FFN, z * (FFN / 2), (z + 1) * (FFN / 2), m0, n0, t, As, Bs, acc);
    int w = t >> 6, lane = t & 63, quad = lane >> 4, l16 = lane & 15;
    int wm = (w >> 1) * 32, wn = (w & 1) * 64;
#pragma unroll
    for (int j = 0; j < 4; j++) {
        int col = n0 + wn + j * 16 + l16;
#pragma unroll
        for (int i = 0; i < 2; i++) {
            int rowb = m0 + wm + i * 16 + quad * 4;
#pragma unroll
            for (int r2 = 0; r2 < 4; r2++)
                P[(size_t)(rowb + r2) * N_EMBD + col] = acc[i][j][r2];
        }
    }
}

// out = p0 + p1 + bias[col] + x1
__global__ __launch_bounds__(256) void reduce_proj(const float* __restrict__ p0,
                                                   const float* __restrict__ p1,
                                                   const float* __restrict__ bias,
                                                   const float* __restrict__ x1,
                                                   float* __restrict__ out) {
    size_t idx = ((size_t)blockIdx.x * 256 + threadIdx.x) * 4;
    int col = (int)(idx % N_EMBD);
    float4 a = *(const float4*)(p0 + idx);
    float4 b = *(const float4*)(p1 + idx);
    float4 r = *(const float4*)(x1 + idx);
    float4 bb = *(const float4*)(bias + col);
    float4 o;
    o.x = a.x + b.x + r.x + bb.x;
    o.y = a.y + b.y + r.y + bb.y;
    o.z = a.z + b.z + r.z + bb.z;
    o.w = a.w + b.w + r.w + bb.w;
    *(float4*)(out + idx) = o;
}

// ---------------- flash cross-attention (round-5 verified) ----------------
#define KST 72

__global__ __launch_bounds__(256) void attn_kernel(const u16* __restrict__ Q,
                                                   const u16* __restrict__ K,
                                                   const u16* __restrict__ V,
                                                   const float* __restrict__ age,
                                                   const float* __restrict__ mod_age,
                                                   u16* __restrict__ Y) {
    __shared__ u16 Kl[64 * KST];
    __shared__ u16 Vt[64 * KST];
    __shared__ u16 Pl[4][16 * KST];

    int bx = blockIdx.x;
    int qt = 15 - (bx / 48);
    int bh = bx % 48;
    int b = bh / NHEAD, h = bh % NHEAD;
    int t = threadIdx.x;
    int w = t >> 6, lane = t & 63, quad = lane >> 4, l16 = lane & 15;
    int q0 = qt * 64 + w * 16;

    size_t qrowbase = ((size_t)(b * SEQ + q0 + l16)) * N_EMBD + h * HDIM;
    bf16x8 qf0 = *(const bf16x8*)&Q[qrowbase + quad * 8];
    bf16x8 qf1 = *(const bf16x8*)&Q[qrowbase + 32 + quad * 8];

    float age_r[4];
#pragma unroll
    for (int r = 0; r < 4; r++) age_r[r] = age[b * SEQ + q0 + quad * 4 + r];
    float age_q0      = __shfl(age_r[0], 0);
    float age_max_blk = age[b * SEQ + qt * 64 + 63];
    float mod_min     = mod_age[b * SEQ];

    float mv0 = (lane < 16) ? mod_age[b * SEQ + lane * 64] : 1e30f;
    unsigned long long bm = __ballot(mv0 > age_max_blk);
    int nkt = bm ? (__ffsll(bm) - 1) : 16;

    int krow0 = t >> 3,        kc8 = (t & 7) * 8;
    int krow1 = 32 + (t >> 3);
    int vrow  = t & 63;
    int vc8_0 = t >> 6, vc8_1 = 4 + (t >> 6);

    float m_i[4] = {-1e30f, -1e30f, -1e30f, -1e30f};
    float l_i[4] = {0.f, 0.f, 0.f, 0.f};
    f32x4 o[4];
#pragma unroll
    for (int nt = 0; nt < 4; nt++) o[nt] = (f32x4){0.f, 0.f, 0.f, 0.f};

    u16x8 kr0, kr1, vr0, vr1;
    float mreg = 0.f;
    if (nkt > 0) {
        size_t kb = ((size_t)(b * SEQ)) * N_EMBD + h * HDIM;
        kr0 = *(const u16x8*)(K + kb + (size_t)krow0 * N_EMBD + kc8);
        kr1 = *(const u16x8*)(K + kb + (size_t)krow1 * N_EMBD + kc8);
        vr0 = *(const u16x8*)(V + kb + (size_t)vrow * N_EMBD + vc8_0 * 8);
        vr1 = *(const u16x8*)(V + kb + (size_t)vrow * N_EMBD + vc8_1 * 8);
        mreg = mod_age[b * SEQ + lane];
    }

    for (int kt = 0; kt < nkt; kt++) {
        __syncthreads();
        *(u16x8*)&Kl[krow0 * KST + kc8] = kr0;
        *(u16x8*)&Kl[krow1 * KST + kc8] = kr1;
#pragma unroll
        for (int e = 0; e < 8; e++) Vt[(vc8_0 * 8 + e) * KST + vrow] = vr0[e];
#pragma unroll
        for (int e = 0; e < 8; e++) Vt[(vc8_1 * 8 + e) * KST + vrow] = vr1[e];
        float mcur = mreg;
        __syncthreads();

        if (kt + 1 < nkt) {
            size_t kb = ((size_t)(b * SEQ + (kt + 1) * 64)) * N_EMBD + h * HDIM;
            kr0 = *(const u16x8*)(K + kb + (size_t)krow0 * N_EMBD + kc8);
            kr1 = *(const u16x8*)(K + kb + (size_t)krow1 * N_EMBD + kc8);
            vr0 = *(const u16x8*)(V + kb + (size_t)vrow * N_EMBD + vc8_0 * 8);
            vr1 = *(const u16x8*)(V + kb + (size_t)vrow * N_EMBD + vc8_1 * 8);
            mreg = mod_age[b * SEQ + (kt + 1) * 64 + lane];
        }

        float tile_max = __shfl(mcur, 63);
        bool need_mask = tile_max > age_q0;
        float p[4][4];
#pragma unroll
        for (int jt = 0; jt < 4; jt++) {
            f32x4 s = (f32x4){0.f, 0.f, 0.f, 0.f};
            bf16x8 kf0 = *(const bf16x8*)&Kl[(jt * 16 + l16) * KST + quad * 8];
            bf16x8 kf1 = *(const bf16x8*)&Kl[(jt * 16 + l16) * KST + 32 + quad * 8];
            s = __builtin_amdgcn_mfma_f32_16x16x32_bf16(qf0, kf0, s, 0, 0, 0);
            s = __builtin_amdgcn_mfma_f32_16x16x32_bf16(qf1, kf1, s, 0, 0, 0);
            float mval = __shfl(mcur, jt * 16 + l16);
#pragma unroll
            for (int r = 0; r < 4; r++) {
                float sv = s[r] * 0.125f;
                p[jt][r] = (!need_mask || mval <= age_r[r]) ? sv : -1e30f;
            }
        }
        float alpha[4];
#pragma unroll
        for (int r = 0; r < 4; r++) {
            float mx = fmaxf(fmaxf(p[0][r], p[1][r]), fmaxf(p[2][r], p[3][r]));
#pragma unroll
            for (int msk = 1; msk < 16; msk <<= 1) mx = fmaxf(mx, __shfl_xor(mx, msk));
            float mnew = fmaxf(m_i[r], mx);
            alpha[r] = __expf(m_i[r] - mnew);
            float srow = 0.f;
#pragma unroll
            for (int jt = 0; jt < 4; jt++) {
                float pv = __expf(p[jt][r] - mnew);
                p[jt][r] = pv;
                srow += pv;
            }
#pragma unroll
            for (int msk = 1; msk < 16; msk <<= 1) srow += __shfl_xor(srow, msk);
            l_i[r] = l_i[r] * alpha[r] + srow;
            m_i[r] = mnew;
        }
#pragma unroll
        for (int jt = 0; jt < 4; jt++)
#pragma unroll
            for (int r = 0; r < 4; r++)
                Pl[w][(quad * 4 + r) * KST + jt * 16 + l16] = f2bf(p[jt][r]);
#pragma unroll
        for (int nt = 0; nt < 4; nt++)
#pragma unroll
            for (int r = 0; r < 4; r++) o[nt][r] *= alpha[r];
#pragma unroll
        for (int c = 0; c < 2; c++) {
            bf16x8 pf = *(const bf16x8*)&Pl[w][l16 * KST + c * 32 + quad * 8];
#pragma unroll
            for (int nt = 0; nt < 4; nt++) {
                bf16x8 vf = *(const bf16x8*)&Vt[(nt * 16 + l16) * KST + c * 32 + quad * 8];
                o[nt] = __builtin_amdgcn_mfma_f32_16x16x32_bf16(pf, vf, o[nt], 0, 0, 0);
            }
        }
    }
#pragma unroll
    for (int r = 0; r < 4; r++) {
        int qrow = q0 + quad * 4 + r;
        float inv = (age_r[r] >= mod_min) ? (1.0f / l_i[r]) : 0.0f;
#pragma unroll
        for (int nt = 0; nt < 4; nt++)
            Y[((size_t)(b * SEQ + qrow)) * N_EMBD + h * HDIM + nt * 16 + l16] =
                f2bf(o[nt][r] * inv);
    }
}

// ---------------- launch ----------------
extern "C" void kernel_launch(void* const* d_in, const int* in_sizes, int n_in,
                              void* d_out, int out_size, void* d_ws, size_t ws_size,
                              hipStream_t stream) {
    const float* x       = (const float*)d_in[0];
    const float* age     = (const float*)d_in[1];
    const int*   mod_idx = (const int*)d_in[2];
    const float* mod_age = (const float*)d_in[3];
    const float* mod2    = (const float*)d_in[4];
    const float* mod3    = (const float*)d_in[5];
    const float* ln0w = (const float*)d_in[6],  *ln0b = (const float*)d_in[7];
    const float* ln1w = (const float*)d_in[8],  *ln1b = (const float*)d_in[9];
    const float* ln2w = (const float*)d_in[10], *ln2b = (const float*)d_in[11];
    const float* qb = (const float*)d_in[13];
    const float* kb = (const float*)d_in[15];
    const float* vb = (const float*)d_in[17];
    const float* cb = (const float*)d_in[19];
    const float* fcb = (const float*)d_in[21];
    const float* pb = (const float*)d_in[23];

    char* ws = (char*)d_ws;
    const size_t RB = (size_t)NROWS * N_EMBD * 2;
    int* g   = (int*)ws;
    u16* wq  = (u16*)(ws + 32768);
    u16* wc  = wq + 3 * (size_t)W768;
    u16* wfc = wq + 4 * (size_t)W768;
    u16* wp  = wq + 4 * (size_t)W768 + WFC;
    size_t off = 32768 + 2 * (4 * (size_t)W768 + 2 * (size_t)WFC);
    u16* xn   = (u16*)(ws + off); off += RB;
    u16* sn   = (u16*)(ws + off); off += RB;
    u16* qbuf = (u16*)(ws + off); off += RB;
    u16* kbuf = (u16*)(ws + off); off += RB;
    u16* vbuf = (u16*)(ws + off); off += RB;
    float* x1 = (float*)(ws + off); off += (size_t)NROWS * N_EMBD * 4;
    u16* hbuf = (u16*)(ws + off);
    u16* yb = xn;  u16* hn = qbuf;
    float* p0 = (float*)xn;    // spans xn+sn
    float* p1 = (float*)kbuf;  // spans kbuf+vbuf

    prep_kernel<<<NCVT + 1024 + NBATCH, 256, 0, stream>>>(
        (const float*)d_in[12], (const float*)d_in[14], (const float*)d_in[16],
        (const float*)d_in[18], (const float*)d_in[20], (const float*)d_in[22], wq,
        x, ln1w, ln1b, xn, mod_idx, g);
    ln_rows<<<NROWS / 4, 256, 0, stream>>>(mod2, mod3, g, ln0w, ln0b, sn);

    gemm_qkv<<<576, 256, 0, stream>>>(xn, sn, wq, qb, kb, vb, qbuf);

    attn_kernel<<<NBATCH * NHEAD * 16, 256, 0, stream>>>(qbuf, kbuf, vbuf, age, mod_age, yb);

    gemm_cproj<<<dim3(N_EMBD / 128, NROWS / 64), 256, 0, stream>>>(yb, wc, cb, x, x1);
    ln_rows<<<NROWS / 4, 256, 0, stream>>>(x1, nullptr, nullptr, ln2w, ln2b, hn);
    gemm_fc<<<768, 256, 0, stream>>>(hn, wfc, fcb, hbuf);
    gemm_proj_split<<<768, 256, 0, stream>>>(hbuf, wp, p0, p1);
    reduce_proj<<<(NROWS * N_EMBD / 4) / 256, 256, 0, stream>>>(p0, p1, pb, x1, (float*)d_out);

    (void)in_sizes; (void)n_in; (void)out_size; (void)ws_size;
}

// Round 11
// 293.546 us; speedup vs baseline: 1.1231x; 1.0201x over previous
//
#include <hip/hip_runtime.h>

#define N_EMBD 768
#define SEQ    1024
#define NBATCH 4
#define NHEAD  12
#define HDIM   64
#define NROWS  4096   // B*L
#define FFN    3072
#define W768   589824    // 768*768
#define WFC    2359296   // 3072*768
#define NCVT   6912      // (4*W768 + 2*WFC) / 1024

typedef unsigned short u16;
typedef __bf16 bf16x8 __attribute__((ext_vector_type(8)));
typedef float  f32x4  __attribute__((ext_vector_type(4)));
typedef unsigned short u16x8 __attribute__((ext_vector_type(8)));

typedef const __attribute__((address_space(1))) unsigned int gu32;
typedef __attribute__((address_space(3))) unsigned int lu32;
#define GLL(g, l) __builtin_amdgcn_global_load_lds((gu32*)(g), (lu32*)(l), 16, 0, 0)

__device__ __forceinline__ u16 f2bf(float f) {
    union { float f; unsigned int i; } v; v.f = f;
    unsigned int r = v.i + 0x7fffu + ((v.i >> 16) & 1u);
    return (u16)(r >> 16);
}

// ---------------- prep: cvt_weights + ln1 + prefix ----------------
__global__ __launch_bounds__(256) void prep_kernel(const float* __restrict__ qw,
                                                   const float* __restrict__ kw,
                                                   const float* __restrict__ vw,
                                                   const float* __restrict__ cw,
                                                   const float* __restrict__ fcw,
                                                   const float* __restrict__ pw,
                                                   u16* __restrict__ wdst,
                                                   const float* __restrict__ x,
                                                   const float* __restrict__ ln1w,
                                                   const float* __restrict__ ln1b,
                                                   u16* __restrict__ xn,
                                                   const int* __restrict__ mod_idx,
                                                   int* __restrict__ g) {
    int bx = blockIdx.x;
    if (bx < NCVT) {
        size_t e = ((size_t)bx * 256 + threadIdx.x) * 4;
        const float* src; size_t base;
        if      (e < 1 * (size_t)W768) { src = qw;  base = 0; }
        else if (e < 2 * (size_t)W768) { src = kw;  base = 1 * (size_t)W768; }
        else if (e < 3 * (size_t)W768) { src = vw;  base = 2 * (size_t)W768; }
        else if (e < 4 * (size_t)W768) { src = cw;  base = 3 * (size_t)W768; }
        else if (e < 4 * (size_t)W768 + WFC) { src = fcw; base = 4 * (size_t)W768; }
        else { src = pw; base = 4 * (size_t)W768 + WFC; }
        float4 v = *(const float4*)(src + (e - base));
        ushort4 o;
        o.x = f2bf(v.x); o.y = f2bf(v.y); o.z = f2bf(v.z); o.w = f2bf(v.w);
        *(ushort4*)(wdst + e) = o;
    } else if (bx < NCVT + 1024) {
        int row  = (bx - NCVT) * 4 + (threadIdx.x >> 6);
        int lane = threadIdx.x & 63;
        const float* p = x + (size_t)row * N_EMBD;
        float vals[12];
        float s = 0.f, sq = 0.f;
#pragma unroll
        for (int c = 0; c < 12; c++) {
            float v = p[c * 64 + lane];
            vals[c] = v; s += v; sq += v * v;
        }
#pragma unroll
        for (int o = 32; o > 0; o >>= 1) { s += __shfl_xor(s, o); sq += __shfl_xor(sq, o); }
        float mean = s * (1.0f / 768.0f);
        float var  = sq * (1.0f / 768.0f) - mean * mean;
        float r    = rsqrtf(var + 1e-5f);
        u16* d = xn + (size_t)row * N_EMBD;
#pragma unroll
        for (int c = 0; c < 12; c++) {
            int idx = c * 64 + lane;
            d[idx] = f2bf((vals[c] - mean) * r * ln1w[idx] + ln1b[idx]);
        }
    } else {
        __shared__ int sc[256];
        int b = bx - NCVT - 1024;
        int j = threadIdx.x;
        int4 mi = *(const int4*)(mod_idx + b * SEQ + j * 4);
        int f0 = (mi.x == 2), f1 = (mi.y == 2), f2v = (mi.z == 2), f3 = (mi.w == 2);
        int t1 = f0 + f1, t2 = t1 + f2v, t3 = t2 + f3;
        sc[j] = t3;
        __syncthreads();
        for (int off = 1; off < 256; off <<= 1) {
            int add = (j >= off) ? sc[j - off] : 0;
            __syncthreads();
            sc[j] += add;
            __syncthreads();
        }
        int excl = sc[j] - t3;
        int cin[4] = {excl + f0, excl + t1, excl + t2, excl + t3};
        int fl[4] = {f0, f1, f2v, f3};
#pragma unroll
        for (int i2 = 0; i2 < 4; i2++) {
            int jj = j * 4 + i2;
            int occ = fl[i2] ? (cin[i2] - 1) : (jj - cin[i2]);
            occ = occ < 0 ? 0 : (occ > 511 ? 511 : occ);
            g[b * SEQ + jj] = fl[i2] ? (b * 512 + occ) : (2048 + b * 512 + occ);
        }
    }
}

// ---------------- LayerNorm (fp32 in, bf16 out), one wave per row ----------------
__global__ __launch_bounds__(256) void ln_rows(const float* __restrict__ src,
                                               const float* __restrict__ src2,
                                               const int* __restrict__ g,
                                               const float* __restrict__ w,
                                               const float* __restrict__ b,
                                               u16* __restrict__ dst) {
    int row  = blockIdx.x * 4 + (threadIdx.x >> 6);
    int lane = threadIdx.x & 63;
    const float* p;
    if (g) {
        int gi = g[row];
        p = (gi < 2048) ? (src + (size_t)gi * N_EMBD)
                        : (src2 + (size_t)(gi - 2048) * N_EMBD);
    } else {
        p = src + (size_t)row * N_EMBD;
    }
    float vals[12];
    float s = 0.f, sq = 0.f;
#pragma unroll
    for (int c = 0; c < 12; c++) {
        float v = p[c * 64 + lane];
        vals[c] = v; s += v; sq += v * v;
    }
#pragma unroll
    for (int o = 32; o > 0; o >>= 1) { s += __shfl_xor(s, o); sq += __shfl_xor(sq, o); }
    float mean = s * (1.0f / 768.0f);
    float var  = sq * (1.0f / 768.0f) - mean * mean;
    float r    = rsqrtf(var + 1e-5f);
    u16* d = dst + (size_t)row * N_EMBD;
#pragma unroll
    for (int c = 0; c < 12; c++) {
        int idx = c * 64 + lane;
        d[idx] = f2bf((vals[c] - mean) * r * w[idx] + b[idx]);
    }
}

// ---------------- GEMM cores: BK=32, GLL staging ----------------
__device__ __forceinline__ void core128(const u16* __restrict__ A, const u16* __restrict__ W,
                                        int K, int m0, int n0, int t,
                                        u16* As, u16* Bs, f32x4 (&acc)[4][4]) {
    int w = t >> 6, lane = t & 63, quad = lane >> 4, l16 = lane & 15;
    int r16 = lane >> 2, c8 = (lane & 3) * 8;
    int wm = (w >> 1) * 64, wn = (w & 1) * 64;
    for (int k0 = 0; k0 < K; k0 += 32) {
        __syncthreads();
        const u16* ga = A + (size_t)(m0 + w * 32 + r16) * K + k0 + c8;
        const u16* gb = W + (size_t)(n0 + w * 32 + r16) * K + k0 + c8;
        GLL(ga,                  &As[(w * 32) * 32]);
        GLL(ga + 16 * (size_t)K, &As[(w * 32 + 16) * 32]);
        GLL(gb,                  &Bs[(w * 32) * 32]);
        GLL(gb + 16 * (size_t)K, &Bs[(w * 32 + 16) * 32]);
        __syncthreads();
        bf16x8 af[4], bfr[4];
#pragma unroll
        for (int i = 0; i < 4; i++)
            af[i] = *(const bf16x8*)&As[(wm + i * 16 + l16) * 32 + quad * 8];
#pragma unroll
        for (int j = 0; j < 4; j++)
            bfr[j] = *(const bf16x8*)&Bs[(wn + j * 16 + l16) * 32 + quad * 8];
#pragma unroll
        for (int i = 0; i < 4; i++)
#pragma unroll
            for (int j = 0; j < 4; j++)
                acc[i][j] = __builtin_amdgcn_mfma_f32_16x16x32_bf16(af[i], bfr[j], acc[i][j], 0, 0, 0);
    }
}

__device__ __forceinline__ void core64(const u16* __restrict__ A, const u16* __restrict__ W,
                                       int K, int kBeg, int kEnd, int m0, int n0, int t,
                                       u16* As, u16* Bs, f32x4 (&acc)[2][4]) {
    int w = t >> 6, lane = t & 63, quad = lane >> 4, l16 = lane & 15;
    int r16 = lane >> 2, c8 = (lane & 3) * 8;
    int wm = (w >> 1) * 32, wn = (w & 1) * 64;
    for (int k0 = kBeg; k0 < kEnd; k0 += 32) {
        __syncthreads();
        const u16* gb = W + (size_t)(n0 + w * 32 + r16) * K + k0 + c8;
        GLL(A + (size_t)(m0 + w * 16 + r16) * K + k0 + c8, &As[(w * 16) * 32]);
        GLL(gb,                  &Bs[(w * 32) * 32]);
        GLL(gb + 16 * (size_t)K, &Bs[(w * 32 + 16) * 32]);
        __syncthreads();
        bf16x8 af[2], bfr[4];
#pragma unroll
        for (int i = 0; i < 2; i++)
            af[i] = *(const bf16x8*)&As[(wm + i * 16 + l16) * 32 + quad * 8];
#pragma unroll
        for (int j = 0; j < 4; j++)
            bfr[j] = *(const bf16x8*)&Bs[(wn + j * 16 + l16) * 32 + quad * 8];
#pragma unroll
        for (int i = 0; i < 2; i++)
#pragma unroll
            for (int j = 0; j < 4; j++)
                acc[i][j] = __builtin_amdgcn_mfma_f32_16x16x32_bf16(af[i], bfr[j], acc[i][j], 0, 0, 0);
    }
}

// ---------------- QKV: 128x128, 1D grid 576, XCD swizzle ----------------
__global__ __launch_bounds__(256) void gemm_qkv(const u16* __restrict__ xn,
                                                const u16* __restrict__ sn,
                                                const u16* __restrict__ wq,
                                                const float* __restrict__ qb,
                                                const float* __restrict__ kb,
                                                const float* __restrict__ vb,
                                                u16* __restrict__ outbase) {
    __shared__ u16 As[128 * 32], Bs[128 * 32];
    int bxg = blockIdx.x;
    int c = bxg & 7, s = bxg >> 3;          // s in [0,72)
    int mg = s / 18, r = s % 18;
    int z = r / 6, n = r % 6;
    int m0 = (mg * 8 + c) * 128, n0 = n * 128;
    const u16* A = (z == 0) ? xn : sn;
    const u16* W = wq + (size_t)z * W768;
    const float* bias = (z == 0) ? qb : ((z == 1) ? kb : vb);
    u16* C = outbase + (size_t)z * ((size_t)NROWS * N_EMBD);
    int t = threadIdx.x;
    f32x4 acc[4][4];
#pragma unroll
    for (int i = 0; i < 4; i++)
#pragma unroll
        for (int j = 0; j < 4; j++) acc[i][j] = (f32x4){0.f, 0.f, 0.f, 0.f};
    core128(A, W, N_EMBD, m0, n0, t, As, Bs, acc);
    int w = t >> 6, lane = t & 63, quad = lane >> 4, l16 = lane & 15;
    int wm = (w >> 1) * 64, wn = (w & 1) * 64;
#pragma unroll
    for (int j = 0; j < 4; j++) {
        int col = n0 + wn + j * 16 + l16;
        float bv = bias[col];
#pragma unroll
        for (int i = 0; i < 4; i++) {
            int rowb = m0 + wm + i * 16 + quad * 4;
#pragma unroll
            for (int r2 = 0; r2 < 4; r2++)
                C[(size_t)(rowb + r2) * N_EMBD + col] = f2bf(acc[i][j][r2] + bv);
        }
    }
}

// ---------------- fc: 128x128, 1D grid 768, XCD swizzle, fast GELU ----------------
__global__ __launch_bounds__(256) void gemm_fc(const u16* __restrict__ A,
                                               const u16* __restrict__ W,
                                               const float* __restrict__ bias,
                                               u16* __restrict__ C) {
    __shared__ u16 As[128 * 32], Bs[128 * 32];
    int bxg = blockIdx.x;
    int c = bxg & 7, s = bxg >> 3;          // s in [0,96)
    int mg = s / 24, n = s % 24;
    int m0 = (mg * 8 + c) * 128, n0 = n * 128;
    int t = threadIdx.x;
    f32x4 acc[4][4];
#pragma unroll
    for (int i = 0; i < 4; i++)
#pragma unroll
        for (int j = 0; j < 4; j++) acc[i][j] = (f32x4){0.f, 0.f, 0.f, 0.f};
    core128(A, W, N_EMBD, m0, n0, t, As, Bs, acc);
    int w = t >> 6, lane = t & 63, quad = lane >> 4, l16 = lane & 15;
    int wm = (w >> 1) * 64, wn = (w & 1) * 64;
#pragma unroll
    for (int j = 0; j < 4; j++) {
        int col = n0 + wn + j * 16 + l16;
        float bv = bias[col];
#pragma unroll
        for (int i = 0; i < 4; i++) {
            int rowb = m0 + wm + i * 16 + quad * 4;
#pragma unroll
            for (int r = 0; r < 4; r++) {
                float v = acc[i][j][r] + bv;
                float y = v * (1.595769122f + 0.071354816f * v * v);
                float gel = v / (1.0f + __expf(-y));
                C[(size_t)(rowb + r) * FFN + col] = f2bf(gel);
            }
        }
    }
}

// ---------------- c-proj: 64x128, 1D grid 384, XCD swizzle, fused epilogue ------
__global__ __launch_bounds__(256) void gemm_cproj(const u16* __restrict__ A,
                                                  const u16* __restrict__ W,
                                                  const float* __restrict__ bias,
                                                  const float* __restrict__ Res,
                                                  float* __restrict__ C) {
    __shared__ u16 As[64 * 32], Bs[128 * 32];
    int bxg = blockIdx.x;
    int c = bxg & 7, s = bxg >> 3;          // s in [0,48)
    int mg = s / 6, n = s % 6;
    int m0 = (mg * 8 + c) * 64, n0 = n * 128;
    int t = threadIdx.x;
    f32x4 acc[2][4];
#pragma unroll
    for (int i = 0; i < 2; i++)
#pragma unroll
        for (int j = 0; j < 4; j++) acc[i][j] = (f32x4){0.f, 0.f, 0.f, 0.f};
    core64(A, W, N_EMBD, 0, N_EMBD, m0, n0, t, As, Bs, acc);
    int w = t >> 6, lane = t & 63, quad = lane >> 4, l16 = lane & 15;
    int wm = (w >> 1) * 32, wn = (w & 1) * 64;
#pragma unroll
    for (int j = 0; j < 4; j++) {
        int col = n0 + wn + j * 16 + l16;
        float bv = bias[col];
#pragma unroll
        for (int i = 0; i < 2; i++) {
            int rowb = m0 + wm + i * 16 + quad * 4;
#pragma unroll
            for (int r = 0; r < 4; r++) {
                size_t idx = (size_t)(rowb + r) * N_EMBD + col;
                C[idx] = acc[i][j][r] + bv + Res[idx];
            }
        }
    }
}

// ---------------- proj: 64x128, K=3072 split-K x2, 1D grid 768, XCD swizzle ------
__global__ __launch_bounds__(256) void gemm_proj_split(const u16* __restrict__ A,
                                                       const u16* __restrict__ W,
                                                       float* __restrict__ p0,
                                                       float* __restrict__ p1) {
    __shared__ u16 As[64 * 32], Bs[128 * 32];
    int bxg = blockIdx.x;
    int c = bxg & 7, s = bxg >> 3;          // s in [0,96)
    int mg = s / 12, r = s % 12;
    int z = r / 6, n = r % 6;
    int m0 = (mg * 8 + c) * 64, n0 = n * 128;
    float* P = z ? p1 : p0;
    int t = threadIdx.x;
    f32x4 acc[2][4];
#pragma unroll
    for (int i = 0; i < 2; i++)
#pragma unroll
        for (int j = 0; j < 4; j++) acc[i][j] = (f32x4){0.f, 0.f, 0.f, 0.f};
    core64(A, W, FFN, z * (FFN / 2), (z + 1) * (FFN / 2), m0, n0, t, As, Bs, acc);
    int w = t >> 6, lane = t & 63, quad = lane >> 4, l16 = lane & 15;
    int wm = (w >> 1) * 32, wn = (w & 1) * 64;
#pragma unroll
    for (int j = 0; j < 4; j++) {
        int col = n0 + wn + j * 16 + l16;
#pragma unroll
        for (int i = 0; i < 2; i++) {
            int rowb = m0 + wm + i * 16 + quad * 4;
#pragma unroll
            for (int r2 = 0; r2 < 4; r2++)
                P[(size_t)(rowb + r2) * N_EMBD + col] = acc[i][j][r2];
        }
    }
}

// out = p0 + p1 + bias[col] + x1
__global__ __launch_bounds__(256) void reduce_proj(const float* __restrict__ p0,
                                                   const float* __restrict__ p1,
                                                   const float* __restrict__ bias,
                                                   const float* __restrict__ x1,
                                                   float* __restrict__ out) {
    size_t idx = ((size_t)blockIdx.x * 256 + threadIdx.x) * 4;
    int col = (int)(idx % N_EMBD);
    float4 a = *(const float4*)(p0 + idx);
    float4 b = *(const float4*)(p1 + idx);
    float4 r = *(const float4*)(x1 + idx);
    float4 bb = *(const float4*)(bias + col);
    float4 o;
    o.x = a.x + b.x + r.x + bb.x;
    o.y = a.y + b.y + r.y + bb.y;
    o.z = a.z + b.z + r.z + bb.z;
    o.w = a.w + b.w + r.w + bb.w;
    *(float4*)(out + idx) = o;
}

// ---------------- flash cross-attention: 128 keys per online-softmax step -------
// Kl [128 keys][64 d] stride 72; Vt [64 d][128 keys] stride 136; Pl per-wave
// [16 q][128 keys] stride 136. Softmax shfl count per iteration unchanged vs
// 64-key version -> per-key overhead halved. Sorted-age mask needs no tail fix.
#define KST2 72
#define VST2 136

__global__ __launch_bounds__(256) void attn_kernel(const u16* __restrict__ Q,
                                                   const u16* __restrict__ K,
                                                   const u16* __restrict__ V,
                                                   const float* __restrict__ age,
                                                   const float* __restrict__ mod_age,
                                                   u16* __restrict__ Y) {
    __shared__ u16 Kl[128 * KST2];
    __shared__ u16 Vt[64 * VST2];
    __shared__ u16 Pl[4][16 * VST2];

    int bx = blockIdx.x;
    int qt = 15 - (bx / 48);          // heavy-first (LPT)
    int bh = bx % 48;
    int b = bh / NHEAD, h = bh % NHEAD;
    int t = threadIdx.x;
    int w = t >> 6, lane = t & 63, quad = lane >> 4, l16 = lane & 15;
    int q0 = qt * 64 + w * 16;

    size_t qrowbase = ((size_t)(b * SEQ + q0 + l16)) * N_EMBD + h * HDIM;
    bf16x8 qf0 = *(const bf16x8*)&Q[qrowbase + quad * 8];
    bf16x8 qf1 = *(const bf16x8*)&Q[qrowbase + 32 + quad * 8];

    float age_r[4];
#pragma unroll
    for (int r = 0; r < 4; r++) age_r[r] = age[b * SEQ + q0 + quad * 4 + r];
    float age_q0      = __shfl(age_r[0], 0);
    float age_max_blk = age[b * SEQ + qt * 64 + 63];
    float mod_min     = mod_age[b * SEQ];

    // valid 64-key tiles, then 128-key iterations
    float mv0 = (lane < 16) ? mod_age[b * SEQ + lane * 64] : 1e30f;
    unsigned long long bm = __ballot(mv0 > age_max_blk);
    int nkt = bm ? (__ffsll(bm) - 1) : 16;
    int nit = (nkt + 1) >> 1;

    // staging: K = 128 rows x 8 chunks (4/thread); V = 128 rows x 8 chunks (4/thread)
    int krow_b = t >> 3, kc8 = (t & 7) * 8;   // K rows i*32 + krow_b, i=0..3
    int vrow   = t & 63, vcb = t >> 6;        // V rows vrow, vrow+64; chunks vcb, vcb+4

    float m_i[4] = {-1e30f, -1e30f, -1e30f, -1e30f};
    float l_i[4] = {0.f, 0.f, 0.f, 0.f};
    f32x4 o[4];
#pragma unroll
    for (int nt = 0; nt < 4; nt++) o[nt] = (f32x4){0.f, 0.f, 0.f, 0.f};

    u16x8 kr[4], vr[4];
    float mreg0 = 0.f, mreg1 = 0.f;
    if (nit > 0) {
        size_t kb = ((size_t)(b * SEQ)) * N_EMBD + h * HDIM;
#pragma unroll
        for (int i = 0; i < 4; i++)
            kr[i] = *(const u16x8*)(K + kb + (size_t)(i * 32 + krow_b) * N_EMBD + kc8);
        vr[0] = *(const u16x8*)(V + kb + (size_t)vrow * N_EMBD + vcb * 8);
        vr[1] = *(const u16x8*)(V + kb + (size_t)vrow * N_EMBD + (vcb + 4) * 8);
        vr[2] = *(const u16x8*)(V + kb + (size_t)(64 + vrow) * N_EMBD + vcb * 8);
        vr[3] = *(const u16x8*)(V + kb + (size_t)(64 + vrow) * N_EMBD + (vcb + 4) * 8);
        mreg0 = mod_age[b * SEQ + lane];
        mreg1 = mod_age[b * SEQ + 64 + lane];
    }

    for (int it = 0; it < nit; it++) {
        __syncthreads();
#pragma unroll
        for (int i = 0; i < 4; i++)
            *(u16x8*)&Kl[(i * 32 + krow_b) * KST2 + kc8] = kr[i];
#pragma unroll
        for (int e = 0; e < 8; e++) {
            Vt[(vcb * 8 + e) * VST2 + vrow]            = vr[0][e];
            Vt[((vcb + 4) * 8 + e) * VST2 + vrow]      = vr[1][e];
            Vt[(vcb * 8 + e) * VST2 + 64 + vrow]       = vr[2][e];
            Vt[((vcb + 4) * 8 + e) * VST2 + 64 + vrow] = vr[3][e];
        }
        float mc0 = mreg0, mc1 = mreg1;
        __syncthreads();

        // prefetch next 128-key block
        if (it + 1 < nit) {
            size_t kb = ((size_t)(b * SEQ + (it + 1) * 128)) * N_EMBD + h * HDIM;
#pragma unroll
            for (int i = 0; i < 4; i++)
                kr[i] = *(const u16x8*)(K + kb + (size_t)(i * 32 + krow_b) * N_EMBD + kc8);
            vr[0] = *(const u16x8*)(V + kb + (size_t)vrow * N_EMBD + vcb * 8);
            vr[1] = *(const u16x8*)(V + kb + (size_t)vrow * N_EMBD + (vcb + 4) * 8);
            vr[2] = *(const u16x8*)(V + kb + (size_t)(64 + vrow) * N_EMBD + vcb * 8);
            vr[3] = *(const u16x8*)(V + kb + (size_t)(64 + vrow) * N_EMBD + (vcb + 4) * 8);
            mreg0 = mod_age[b * SEQ + (it + 1) * 128 + lane];
            mreg1 = mod_age[b * SEQ + (it + 1) * 128 + 64 + lane];
        }

        // S = Q K^T * scale (+ mask; sorted ages kill any key beyond nkt)
        float tile_max = __shfl(mc1, 63);
        bool need_mask = tile_max > age_q0;
        float p[8][4];
#pragma unroll
        for (int jt = 0; jt < 8; jt++) {
            f32x4 s = (f32x4){0.f, 0.f, 0.f, 0.f};
            bf16x8 kf0 = *(const bf16x8*)&Kl[(jt * 16 + l16) * KST2 + quad * 8];
            bf16x8 kf1 = *(const bf16x8*)&Kl[(jt * 16 + l16) * KST2 + 32 + quad * 8];
            s = __builtin_amdgcn_mfma_f32_16x16x32_bf16(qf0, kf0, s, 0, 0, 0);
            s = __builtin_amdgcn_mfma_f32_16x16x32_bf16(qf1, kf1, s, 0, 0, 0);
            float mval = (jt < 4) ? __shfl(mc0, jt * 16 + l16)
                                  : __shfl(mc1, (jt - 4) * 16 + l16);
#pragma unroll
            for (int r = 0; r < 4; r++) {
                float sv = s[r] * 0.125f;
                p[jt][r] = (!need_mask || mval <= age_r[r]) ? sv : -1e30f;
            }
        }
        // online softmax over 128 keys
        float alpha[4];
#pragma unroll
        for (int r = 0; r < 4; r++) {
            float mx = p[0][r];
#pragma unroll
            for (int jt = 1; jt < 8; jt++) mx = fmaxf(mx, p[jt][r]);
#pragma unroll
            for (int msk = 1; msk < 16; msk <<= 1) mx = fmaxf(mx, __shfl_xor(mx, msk));
            float mnew = fmaxf(m_i[r], mx);
            alpha[r] = __expf(m_i[r] - mnew);
            float srow = 0.f;
#pragma unroll
            for (int jt = 0; jt < 8; jt++) {
                float pv = __expf(p[jt][r] - mnew);
                p[jt][r] = pv;
                srow += pv;
            }
#pragma unroll
            for (int msk = 1; msk < 16; msk <<= 1) srow += __shfl_xor(srow, msk);
            l_i[r] = l_i[r] * alpha[r] + srow;
            m_i[r] = mnew;
        }
        // P -> LDS (C layout -> A layout), rescale O, O += P V
#pragma unroll
        for (int jt = 0; jt < 8; jt++)
#pragma unroll
            for (int r = 0; r < 4; r++)
                Pl[w][(quad * 4 + r) * VST2 + jt * 16 + l16] = f2bf(p[jt][r]);
#pragma unroll
        for (int nt = 0; nt < 4; nt++)
#pragma unroll
            for (int r = 0; r < 4; r++) o[nt][r] *= alpha[r];
#pragma unroll
        for (int c = 0; c < 4; c++) {
            bf16x8 pf = *(const bf16x8*)&Pl[w][l16 * VST2 + c * 32 + quad * 8];
#pragma unroll
            for (int nt = 0; nt < 4; nt++) {
                bf16x8 vf = *(const bf16x8*)&Vt[(nt * 16 + l16) * VST2 + c * 32 + quad * 8];
                o[nt] = __builtin_amdgcn_mfma_f32_16x16x32_bf16(pf, vf, o[nt], 0, 0, 0);
            }
        }
    }
#pragma unroll
    for (int r = 0; r < 4; r++) {
        int qrow = q0 + quad * 4 + r;
        float inv = (age_r[r] >= mod_min) ? (1.0f / l_i[r]) : 0.0f;
#pragma unroll
        for (int nt = 0; nt < 4; nt++)
            Y[((size_t)(b * SEQ + qrow)) * N_EMBD + h * HDIM + nt * 16 + l16] =
                f2bf(o[nt][r] * inv);
    }
}

// ---------------- launch ----------------
extern "C" void kernel_launch(void* const* d_in, const int* in_sizes, int n_in,
                              void* d_out, int out_size, void* d_ws, size_t ws_size,
                              hipStream_t stream) {
    const float* x       = (const float*)d_in[0];
    const float* age     = (const float*)d_in[1];
    const int*   mod_idx = (const int*)d_in[2];
    const float* mod_age = (const float*)d_in[3];
    const float* mod2    = (const float*)d_in[4];
    const float* mod3    = (const float*)d_in[5];
    const float* ln0w = (const float*)d_in[6],  *ln0b = (const float*)d_in[7];
    const float* ln1w = (const float*)d_in[8],  *ln1b = (const float*)d_in[9];
    const float* ln2w = (const float*)d_in[10], *ln2b = (const float*)d_in[11];
    const float* qb = (const float*)d_in[13];
    const float* kb = (const float*)d_in[15];
    const float* vb = (const float*)d_in[17];
    const float* cb = (const float*)d_in[19];
    const float* fcb = (const float*)d_in[21];
    const float* pb = (const float*)d_in[23];

    char* ws = (char*)d_ws;
    const size_t RB = (size_t)NROWS * N_EMBD * 2;
    int* g   = (int*)ws;
    u16* wq  = (u16*)(ws + 32768);
    u16* wc  = wq + 3 * (size_t)W768;
    u16* wfc = wq + 4 * (size_t)W768;
    u16* wp  = wq + 4 * (size_t)W768 + WFC;
    size_t off = 32768 + 2 * (4 * (size_t)W768 + 2 * (size_t)WFC);
    u16* xn   = (u16*)(ws + off); off += RB;
    u16* sn   = (u16*)(ws + off); off += RB;
    u16* qbuf = (u16*)(ws + off); off += RB;
    u16* kbuf = (u16*)(ws + off); off += RB;
    u16* vbuf = (u16*)(ws + off); off += RB;
    float* x1 = (float*)(ws + off); off += (size_t)NROWS * N_EMBD * 4;
    u16* hbuf = (u16*)(ws + off);
    u16* yb = xn;  u16* hn = qbuf;
    float* p0 = (float*)xn;    // spans xn+sn
    float* p1 = (float*)kbuf;  // spans kbuf+vbuf

    prep_kernel<<<NCVT + 1024 + NBATCH, 256, 0, stream>>>(
        (const float*)d_in[12], (const float*)d_in[14], (const float*)d_in[16],
        (const float*)d_in[18], (const float*)d_in[20], (const float*)d_in[22], wq,
        x, ln1w, ln1b, xn, mod_idx, g);
    ln_rows<<<NROWS / 4, 256, 0, stream>>>(mod2, mod3, g, ln0w, ln0b, sn);

    gemm_qkv<<<576, 256, 0, stream>>>(xn, sn, wq, qb, kb, vb, qbuf);

    attn_kernel<<<NBATCH * NHEAD * 16, 256, 0, stream>>>(qbuf, kbuf, vbuf, age, mod_age, yb);

    gemm_cproj<<<384, 256, 0, stream>>>(yb, wc, cb, x, x1);
    ln_rows<<<NROWS / 4, 256, 0, stream>>>(x1, nullptr, nullptr, ln2w, ln2b, hn);
    gemm_fc<<<768, 256, 0, stream>>>(hn, wfc, fcb, hbuf);
    gemm_proj_split<<<768, 256, 0, stream>>>(hbuf, wp, p0, p1);
    reduce_proj<<<(NROWS * N_EMBD / 4) / 256, 256, 0, stream>>>(p0, p1, pb, x1, (float*)d_out);

    (void)in_sizes; (void)n_in; (void)out_size; (void)ws_size;
}